// Round 10
// baseline (793.824 us; speedup 1.0000x reference)
//
#include <hip/hip_runtime.h>

#define HW 65536
#define NSP 1024
#define NE 524288
#define NCLS 16
#define BN_EPS 1e-5f
#define LSLOPE 0.01f

typedef unsigned short u16;
typedef short s16x8 __attribute__((ext_vector_type(8)));
typedef u16 u16x8 __attribute__((ext_vector_type(8)));
typedef u16 u16x4 __attribute__((ext_vector_type(4)));
typedef u16 u16x2 __attribute__((ext_vector_type(2)));
typedef float f32x4 __attribute__((ext_vector_type(4)));

__device__ inline u16 f2b(float x) {            // f32 -> bf16 RNE
  unsigned int u = __float_as_uint(x);
  unsigned int r = ((u >> 16) & 1u) + 0x7FFFu;
  return (u16)((u + r) >> 16);
}
__device__ inline float b2f(u16 u) { return __uint_as_float(((unsigned int)u) << 16); }

struct P {
  const float *x, *Q, *A_norm;
  const int *e_src, *e_dst;
  const float *preW, *preB;
  const float *g1W, *g1b, *g2W, *g2b;
  const float *m1W, *m1b, *m2W, *m2b;
  const float *oW, *ob;
  float *outp;
  float *bufA, *bufB;
  int *cntd, *cntinv;
  float *stats;                       // 5 pairs of (sum[128], sumsq[128])
  float *spDp, *spHp;
  int *seg, *seginv, *offp, *cur;
  float *dinv;
  int2 *e2;
  int *bsum;
  float *spA;
  float *xn1, *xn2, *z1p, *z2p, *rsums;
  float *rowss, *invM2;
  float *WppG1, *WppG2;
  u16 *WTm1, *WTm2, *WTpre;
  float *cvG1, *bpG1, *cvG2, *bpG2, *cvM1, *bpM1, *cvM2, *bpM2;
  float *invG1, *invG2, *invM1;
  u16 *xb, *xwB, *bufN;
};

#define S_A(p)  ((p).stats + 0*256)
#define S_G1(p) ((p).stats + 1*256)
#define S_G2(p) ((p).stats + 2*256)
#define S_M1(p) ((p).stats + 3*256)
#define S_M2(p) ((p).stats + 4*256)

#define NQB 4096
#define NDB (NE / 256)
#define CXB (HW * 56 / 256)
#define CWB 112
#define RSB 256

// == k_setup: seg/seg_inv (early-exit one-hot scan) + degree + x->bf16 + preW->bf16T + A rowsums ==
__global__ __launch_bounds__(256) void k_setup(P p) {
  int b = blockIdx.x, t = threadIdx.x;
  int wv = t >> 6, lane = t & 63;
  if (b < NQB) {
    #pragma unroll
    for (int rr = 0; rr < 4; ++rr) {
      int row = (b * 4 + wv) * 4 + rr;
      const float4* qrow = (const float4*)(p.Q + (size_t)row * NSP);
      for (int c = 0; c < 4; ++c) {
        float4 v = qrow[c * 64 + lane];
        int hit = (v.x > 0.5f) || (v.y > 0.5f) || (v.z > 0.5f) || (v.w > 0.5f);
        unsigned long long m = __ballot(hit);
        if (m) {
          int L = (int)__ffsll((unsigned long long)m) - 1;
          if (lane == L) {
            int comp = (v.x > 0.5f) ? 0 : (v.y > 0.5f) ? 1 : (v.z > 0.5f) ? 2 : 3;
            int s = c * 256 + lane * 4 + comp;
            p.seg[row] = s;
            int pos = atomicAdd(&p.cntinv[s], 1);
            p.seginv[s * 64 + pos] = row;
          }
          break;
        }
      }
    }
  } else if (b < NQB + NDB) {
    int e = (b - NQB) * 256 + t;
    if (e < NE) atomicAdd(&p.cntd[p.e_dst[e]], 1);
  } else if (b < NQB + NDB + CXB) {
    int g = (b - NQB - NDB) * 256 + t;
    int row = g / 56, qd = g - row * 56;
    int k0 = qd * 4;
    u16x4 o;
    if (k0 < 200) {
      float4 v = *(const float4*)&p.x[(size_t)row * 200 + k0];
      o[0] = f2b(v.x); o[1] = f2b(v.y); o[2] = f2b(v.z); o[3] = f2b(v.w);
    } else { o[0] = 0; o[1] = 0; o[2] = 0; o[3] = 0; }
    *(u16x4*)&p.xb[(size_t)row * 224 + k0] = o;
  } else if (b < NQB + NDB + CXB + CWB) {
    int g = (b - NQB - NDB - CXB) * 256 + t;
    if (g < 128 * 224) {
      int n = g / 224, k = g - n * 224;
      p.WTpre[g] = (k < 200) ? f2b(p.preW[(size_t)k * 128 + n]) : (u16)0;
    }
  } else {
    int row = (b - NQB - NDB - CXB - CWB) * 4 + wv;
    const float4* ar = (const float4*)(p.A_norm + (size_t)row * NSP);
    float s = 0.f;
    #pragma unroll
    for (int c = 0; c < 4; ++c) {
      float4 v = ar[c * 64 + lane];
      s += v.x + v.y + v.z + v.w;
    }
    #pragma unroll
    for (int o = 1; o < 64; o <<= 1) s += __shfl_xor(s, o);
    if (lane == 0) p.rsums[row] = s;
  }
}

// =========================== device: scan_a =====================================
__device__ void dev_scan_a(P& p, int b, char* smem) {
  int* s = (int*)smem;
  int t = threadIdx.x;
  int i = b * 256 + t;
  int v = p.cntd[i];
  s[t] = v; __syncthreads();
  for (int o = 1; o < 256; o <<= 1) {
    int x = (t >= o) ? s[t - o] : 0;
    __syncthreads();
    s[t] += x;
    __syncthreads();
  }
  p.offp[i] = s[t] - v;
  if (t == 255) p.bsum[b] = s[t];
}

// ================== device: scan_c2 (merged scan_b + scan_c) ====================
__device__ void dev_scan_c2(P& p, int b, char* smem) {
  int* w4 = (int*)smem;
  int t = threadIdx.x;
  int v = (t < b) ? p.bsum[t] : 0;
  #pragma unroll
  for (int o = 1; o < 64; o <<= 1) v += __shfl_xor(v, o);
  if ((t & 63) == 0) w4[t >> 6] = v;
  __syncthreads();
  int base = w4[0] + w4[1] + w4[2] + w4[3];
  int i = b * 256 + t;
  int ov = p.offp[i] + base;
  p.offp[i] = ov;
  p.cur[i] = ov;
  p.dinv[i] = rsqrtf((float)p.cntd[i] + 1.0f);
  if (i == 0) p.offp[HW] = NE;
}

// ============================ device: scatter ====================================
__device__ void dev_scatter(P& p, int b) {
  int e = b * 256 + threadIdx.x;
  if (e < NE) {
    int d = p.e_dst[e], s = p.e_src[e];
    float w = p.dinv[d] * p.dinv[s];
    int pos = atomicAdd(&p.cur[d], 1);
    p.e2[pos] = make_int2(s, __float_as_int(w));
  }
}

// ====================== device: MFMA bf16 GEMM (needs 31744B smem) ===============
__device__ void dev_mgemm(const void* Ap, int a_bf16, int lda,
                          const u16* WT, int ldb, int K,
                          const float* bias, const float* cvec, const float* invn,
                          void* Cp, int c_bf16,
                          float* sums, float* sumsq, int bid, char* smem) {
  u16* As = (u16*)smem;                 // [2][64][40]
  u16* Bs = (u16*)(smem + 10240);       // [2][128][40]
  float* lsum = (float*)(smem + 30720);
  float* lssq = lsum + 128;
  int t = threadIdx.x;
  if (sums && t < 128) { lsum[t] = 0.f; lssq[t] = 0.f; }
  int row0 = bid * 64;
  int ar = t >> 2, ak = (t & 3) * 8;
  u16x8 aReg; u16x8 bReg[2];

  auto loadRegs = [&](int k0) {
    if (a_bf16) {
      aReg = *(const u16x8*)((const u16*)Ap + (size_t)(row0 + ar) * lda + k0 + ak);
    } else {
      const float* ap = (const float*)Ap + (size_t)(row0 + ar) * lda + k0 + ak;
      float4 f0 = *(const float4*)ap;
      float4 f1 = *(const float4*)(ap + 4);
      u16x8 v;
      v[0] = f2b(f0.x); v[1] = f2b(f0.y); v[2] = f2b(f0.z); v[3] = f2b(f0.w);
      v[4] = f2b(f1.x); v[5] = f2b(f1.y); v[6] = f2b(f1.z); v[7] = f2b(f1.w);
      aReg = v;
    }
    #pragma unroll
    for (int it = 0; it < 2; ++it) {
      int slot = t + it * 256;
      int bn = slot >> 2, kg = (slot & 3) * 8;
      bReg[it] = *(const u16x8*)(WT + (size_t)bn * ldb + k0 + kg);
    }
  };
  auto dsWrite = [&](int bq) {
    *(u16x8*)&As[(bq * 64 + ar) * 40 + ak] = aReg;
    #pragma unroll
    for (int it = 0; it < 2; ++it) {
      int slot = t + it * 256;
      int bn = slot >> 2, kg = (slot & 3) * 8;
      *(u16x8*)&Bs[(bq * 128 + bn) * 40 + kg] = bReg[it];
    }
  };

  int lane = t & 63, wvv = t >> 6;
  int m0 = (wvv >> 1) * 32, n0 = (wvv & 1) * 64;
  int fr = lane & 15, fk = (lane >> 4) * 8;
  f32x4 acc[2][4];
  #pragma unroll
  for (int mt = 0; mt < 2; ++mt)
    #pragma unroll
    for (int nt = 0; nt < 4; ++nt)
      acc[mt][nt] = (f32x4){0.f, 0.f, 0.f, 0.f};

  int nch = K >> 5;
  loadRegs(0);
  int cur = 0;
  for (int ch = 0; ch < nch; ++ch) {
    dsWrite(cur);
    __syncthreads();
    if (ch + 1 < nch) loadRegs((ch + 1) << 5);
    s16x8 afr0 = *(const s16x8*)&As[(cur * 64 + m0 + fr) * 40 + fk];
    s16x8 afr1 = *(const s16x8*)&As[(cur * 64 + m0 + 16 + fr) * 40 + fk];
    s16x8 bfr[4];
    #pragma unroll
    for (int nt = 0; nt < 4; ++nt)
      bfr[nt] = *(const s16x8*)&Bs[(cur * 128 + n0 + nt * 16 + fr) * 40 + fk];
    #pragma unroll
    for (int nt = 0; nt < 4; ++nt) {
      acc[0][nt] = __builtin_amdgcn_mfma_f32_16x16x32_bf16(afr0, bfr[nt], acc[0][nt], 0, 0, 0);
      acc[1][nt] = __builtin_amdgcn_mfma_f32_16x16x32_bf16(afr1, bfr[nt], acc[1][nt], 0, 0, 0);
    }
    cur ^= 1;
  }

  float bb4[4], cv4[4];
  #pragma unroll
  for (int nt = 0; nt < 4; ++nt) {
    int c = n0 + nt * 16 + fr;
    bb4[nt] = bias ? bias[c] : 0.f;
    cv4[nt] = cvec ? cvec[c] : 0.f;
  }
  int rg = lane >> 4;
  float cs4[4] = {}, cq4[4] = {};
  #pragma unroll
  for (int mt = 0; mt < 2; ++mt) {
    int rbase = row0 + m0 + mt * 16 + rg * 4;
    float inr[4];
    #pragma unroll
    for (int j = 0; j < 4; ++j) inr[j] = invn ? invn[rbase + j] : 1.f;
    #pragma unroll
    for (int nt = 0; nt < 4; ++nt) {
      int c = n0 + nt * 16 + fr;
      #pragma unroll
      for (int j = 0; j < 4; ++j) {
        float xv = inr[j] * (acc[mt][nt][j] - cv4[nt]) + bb4[nt];
        if (sums) { cs4[nt] += xv; cq4[nt] += xv * xv; }
        if (c_bf16) ((u16*)Cp)[(size_t)(rbase + j) * 128 + c] = f2b(xv);
        else        ((float*)Cp)[(size_t)(rbase + j) * 128 + c] = xv;
      }
    }
  }
  if (sums) {
    __syncthreads();
    #pragma unroll
    for (int nt = 0; nt < 4; ++nt) {
      int c = n0 + nt * 16 + fr;
      atomicAdd(&lsum[c], cs4[nt]);
      atomicAdd(&lssq[c], cq4[nt]);
    }
    __syncthreads();
    if (t < 128) { atomicAdd(&sums[t], lsum[t]); atomicAdd(&sumsq[t], lssq[t]); }
  }
}

// =================== device: superpixel mean-pool (4096B smem) ==================
__device__ void dev_pool2(P& p, int sp, char* smem) {
  float4* part = (float4*)smem;   // [8][32]
  int t = threadIdx.x;
  int l32 = t & 31, g = t >> 5;
  int cnt = p.cntinv[sp];
  const float4* y4 = (const float4*)p.bufA;
  const int* lst = p.seginv + sp * 64;
  float4 acc = make_float4(0.f, 0.f, 0.f, 0.f);
  int r = g;
  for (; r + 8 < cnt; r += 16) {
    int i0 = lst[r], i1 = lst[r + 8];
    float4 a = y4[(size_t)i0 * 32 + l32];
    float4 b = y4[(size_t)i1 * 32 + l32];
    acc.x += a.x + b.x; acc.y += a.y + b.y;
    acc.z += a.z + b.z; acc.w += a.w + b.w;
  }
  for (; r < cnt; r += 8) {
    float4 a = y4[(size_t)lst[r] * 32 + l32];
    acc.x += a.x; acc.y += a.y; acc.z += a.z; acc.w += a.w;
  }
  part[g * 32 + l32] = acc;
  __syncthreads();
  if (g == 0) {
    float4 s = part[l32];
    #pragma unroll
    for (int q = 1; q < 8; ++q) {
      float4 pp = part[q * 32 + l32];
      s.x += pp.x; s.y += pp.y; s.z += pp.z; s.w += pp.w;
    }
    int d0 = l32 * 4;
    const float* sAs = S_A(p);
    const float* sAq = S_A(p) + 128;
    float4 ss = *(const float4*)&sAs[d0];
    float4 sq = *(const float4*)&sAq[d0];
    float inv = 1.0f / (float)cnt;
    float4 o;
    float m, rs;
    m = ss.x / HW; rs = rsqrtf(sq.x / HW - m * m + BN_EPS); o.x = (s.x * inv - m) * rs;
    m = ss.y / HW; rs = rsqrtf(sq.y / HW - m * m + BN_EPS); o.y = (s.y * inv - m) * rs;
    m = ss.z / HW; rs = rsqrtf(sq.z / HW - m * m + BN_EPS); o.z = (s.z * inv - m) * rs;
    m = ss.w / HW; rs = rsqrtf(sq.w / HW - m * m + BN_EPS); o.w = (s.w * inv - m) * rs;
    *(float4*)&p.spA[sp * 128 + d0] = o;
  }
}

// == device: row inv-norms + col-stats of normalized; optional normalized write ==
__device__ void dev_rstats(const float* in, float* norm_out, float* invn,
                           float* sums, float* sumsq, int M,
                           const float* preS, const float* preQ, float precnt,
                           int leaky_in, int bid, int nb, char* smem) {
  float* lsum = (float*)smem;
  float* lssq = lsum + 128;
  int t = threadIdx.x;
  if (t < 128) { lsum[t] = 0.f; lssq[t] = 0.f; }
  __syncthreads();
  int wid = t >> 6, lane = t & 63, d0 = lane * 2;
  float m0 = 0.f, m1 = 0.f, r0 = 1.f, r1 = 1.f;
  if (preS) {
    m0 = preS[d0] / precnt;
    r0 = rsqrtf(preQ[d0] / precnt - m0 * m0 + BN_EPS);
    m1 = preS[d0 + 1] / precnt;
    r1 = rsqrtf(preQ[d0 + 1] / precnt - m1 * m1 + BN_EPS);
  }
  float cs0 = 0.f, cs1 = 0.f, cq0 = 0.f, cq1 = 0.f;
  for (int row = bid * 4 + wid; row < M; row += nb * 4) {
    float2 v = *(const float2*)(in + (size_t)row * 128 + d0);
    v.x = (v.x - m0) * r0;
    v.y = (v.y - m1) * r1;
    if (leaky_in) {
      v.x = (v.x >= 0.f) ? v.x : LSLOPE * v.x;
      v.y = (v.y >= 0.f) ? v.y : LSLOPE * v.y;
    }
    float ss = v.x * v.x + v.y * v.y;
    #pragma unroll
    for (int o = 1; o < 64; o <<= 1) ss += __shfl_xor(ss, o);
    float sc = 1.0f / fmaxf(sqrtf(ss), 1e-12f);
    if (lane == 0) invn[row] = sc;
    float nx = v.x * sc, ny = v.y * sc;
    if (norm_out) *(float2*)(norm_out + (size_t)row * 128 + d0) = make_float2(nx, ny);
    cs0 += nx; cs1 += ny; cq0 += nx * nx; cq1 += ny * ny;
  }
  atomicAdd(&lsum[d0], cs0); atomicAdd(&lsum[d0 + 1], cs1);
  atomicAdd(&lssq[d0], cq0); atomicAdd(&lssq[d0 + 1], cq1);
  __syncthreads();
  if (t < 128) { atomicAdd(&sums[t], lsum[t]); atomicAdd(&sumsq[t], lssq[t]); }
}

// ====== device: fold BN(s) into W -> optional Wpp(f32) / WT(bf16 T) (8192B) =====
__device__ void dev_prepw(const float* sums, const float* sumsq, float cnt,
                          const float* W, const float* base,
                          const float* preS, const float* preQ, float precnt,
                          float* Wpp, u16* WT, float* cvec, float* bp, char* smem) {
  float* redc = (float*)smem;            // [8][128]
  float* redb = redc + 1024;
  int t = threadIdx.x;
  int kq = (t & 31) * 4, jg = t >> 5;
  float cx = 0.f, cy = 0.f, cz = 0.f, cw = 0.f;
  float bx = 0.f, by = 0.f, bz = 0.f, bw = 0.f;
  for (int j = jg; j < 128; j += 8) {
    float m2 = sums[j] / cnt;
    float rs2 = rsqrtf(sumsq[j] / cnt - m2 * m2 + BN_EPS);
    float mA = 0.f, rsA = 1.f;
    if (preS) {
      mA = preS[j] / precnt;
      rsA = rsqrtf(preQ[j] / precnt - mA * mA + BN_EPS);
    }
    float4 w = *(const float4*)&W[j * 128 + kq];
    float sA = rsA * rs2;
    float4 wpp = make_float4(sA * w.x, sA * w.y, sA * w.z, sA * w.w);
    if (Wpp) *(float4*)&Wpp[j * 128 + kq] = wpp;
    if (WT) {
      WT[(size_t)(kq + 0) * 128 + j] = f2b(wpp.x);
      WT[(size_t)(kq + 1) * 128 + j] = f2b(wpp.y);
      WT[(size_t)(kq + 2) * 128 + j] = f2b(wpp.z);
      WT[(size_t)(kq + 3) * 128 + j] = f2b(wpp.w);
    }
    cx = fmaf(mA, wpp.x, cx); cy = fmaf(mA, wpp.y, cy);
    cz = fmaf(mA, wpp.z, cz); cw = fmaf(mA, wpp.w, cw);
    float m2s = m2 * rs2;
    bx = fmaf(m2s, w.x, bx); by = fmaf(m2s, w.y, by);
    bz = fmaf(m2s, w.z, bz); bw = fmaf(m2s, w.w, bw);
  }
  *(float4*)&redc[jg * 128 + kq] = make_float4(cx, cy, cz, cw);
  *(float4*)&redb[jg * 128 + kq] = make_float4(bx, by, bz, bw);
  __syncthreads();
  if (t < 32) {
    int k4 = t * 4;
    float4 sc = *(float4*)&redc[k4];
    float4 sb = *(float4*)&redb[k4];
    #pragma unroll
    for (int g = 1; g < 8; ++g) {
      float4 ac = *(float4*)&redc[g * 128 + k4];
      float4 ab = *(float4*)&redb[g * 128 + k4];
      sc.x += ac.x; sc.y += ac.y; sc.z += ac.z; sc.w += ac.w;
      sb.x += ab.x; sb.y += ab.y; sb.z += ab.z; sb.w += ab.w;
    }
    *(float4*)&cvec[k4] = sc;
    float4 bs = base ? *(const float4*)&base[k4] : make_float4(0, 0, 0, 0);
    *(float4*)&bp[k4] = make_float4(bs.x - sb.x, bs.y - sb.y, bs.z - sb.z, bs.w - sb.w);
  }
}

// ====== device: COLUMN-SPLIT CSR edge agg: 16 cols/group, L2-resident slice =====
// bid in [0,2048): group g = bid&7 (XCD-aligned), chunk = bid>>3 (256 rows).
// mode 1: write bf16 m1 (unnormalized) + per-row sumsq atomics; mode 0: f32 out.
__device__ void dev_agg_cs(P& p, const u16* tbl, const float* bias, void* outp,
                           int mode, float* rowss, int bid) {
  int t = threadIdx.x;
  int wv = t >> 6, lane = t & 63;
  int slot = lane >> 3, cl = lane & 7;
  int g = bid & 7;
  int c0 = g * 16 + cl * 2;
  int rowbase = (bid >> 3) * 256 + wv * 64;
  float b0 = bias[c0], b1 = bias[c0 + 1];
  for (int r = 0; r < 64; ++r) {
    int i = rowbase + r;
    int s0 = p.offp[i], s1 = p.offp[i + 1];
    float a0 = 0.f, a1 = 0.f;
    for (int kk = s0; kk < s1; kk += 8) {
      int idx = kk + slot;
      if (idx < s1) {
        int2 e = p.e2[idx];
        float w = __int_as_float(e.y);
        u16x2 v = *(const u16x2*)&tbl[(size_t)e.x * 128 + c0];
        a0 = fmaf(w, b2f(v[0]), a0);
        a1 = fmaf(w, b2f(v[1]), a1);
      }
    }
    a0 += __shfl_xor(a0, 8);  a1 += __shfl_xor(a1, 8);
    a0 += __shfl_xor(a0, 16); a1 += __shfl_xor(a1, 16);
    a0 += __shfl_xor(a0, 32); a1 += __shfl_xor(a1, 32);
    float di = p.dinv[i];
    if (slot == 0) {
      u16x2 xi = *(const u16x2*)&tbl[(size_t)i * 128 + c0];
      float inv_deg = di * di;
      float r0 = fmaf(b2f(xi[0]), inv_deg, a0) + b0;
      float r1 = fmaf(b2f(xi[1]), inv_deg, a1) + b1;
      r0 = (r0 >= 0.f) ? r0 : LSLOPE * r0;
      r1 = (r1 >= 0.f) ? r1 : LSLOPE * r1;
      if (mode) {
        u16x2 o; o[0] = f2b(r0); o[1] = f2b(r1);
        *(u16x2*)&((u16*)outp)[(size_t)i * 128 + c0] = o;
        float pq = r0 * r0 + r1 * r1;
        pq += __shfl_xor(pq, 1); pq += __shfl_xor(pq, 2); pq += __shfl_xor(pq, 4);
        if (cl == 0) atomicAdd(&rowss[i], pq);
      } else {
        *(float2*)&((float*)outp)[(size_t)i * 128 + c0] = make_float2(r0, r1);
      }
    }
  }
}

// == device: phase B: invn from rowss + col-stats of normalized m1 (1024B smem) ==
__device__ void dev_phaseB(P& p, int bid, int nb, char* smem) {
  float* lsum = (float*)smem;
  float* lssq = lsum + 128;
  int t = threadIdx.x;
  if (t < 128) { lsum[t] = 0.f; lssq[t] = 0.f; }
  __syncthreads();
  int wid = t >> 6, lane = t & 63, d0 = lane * 2;
  float cs0 = 0.f, cs1 = 0.f, cq0 = 0.f, cq1 = 0.f;
  for (int row = bid * 4 + wid; row < HW; row += nb * 4) {
    u16x2 v = *(const u16x2*)&p.bufN[(size_t)row * 128 + d0];
    float ss = p.rowss[row];
    float sc = 1.0f / fmaxf(sqrtf(ss), 1e-12f);
    if (lane == 0) p.invM2[row] = sc;
    float nx = b2f(v[0]) * sc, ny = b2f(v[1]) * sc;
    cs0 += nx; cs1 += ny; cq0 += nx * nx; cq1 += ny * ny;
  }
  atomicAdd(&lsum[d0], cs0); atomicAdd(&lsum[d0 + 1], cs1);
  atomicAdd(&lssq[d0], cq0); atomicAdd(&lssq[d0 + 1], cq1);
  __syncthreads();
  if (t < 128) { atomicAdd(&S_M2(p)[t], lsum[t]); atomicAdd(&(S_M2(p) + 128)[t], lssq[t]); }
}

// == device: small GEMM [1024x128]@[128x128] tail: out = Z@W + rs[row]*bp[col] ===
__device__ void dev_gemm_tail(const float* Z, const float* W,
                              const float* bp, const float* rs,
                              float* out, int bid) {
  int t = threadIdx.x;
  int c = t & 127, rh = t >> 7;
  int row0 = bid * 16 + rh * 8;
  float acc[8] = {};
  const float* ip = Z + (size_t)row0 * 128;
  #pragma unroll 4
  for (int k = 0; k < 128; ++k) {
    float w = W[k * 128 + c];
    #pragma unroll
    for (int i = 0; i < 8; ++i)
      acc[i] = fmaf(ip[(size_t)i * 128 + k], w, acc[i]);
  }
  float bpc = bp[c];
  #pragma unroll
  for (int i = 0; i < 8; ++i) {
    int row = row0 + i;
    out[(size_t)row * 128 + c] = acc[i] + rs[row] * bpc;
  }
}

// ===== device: split-K GEMM A_norm[1024x1024]@Xn -> atomic out (25088B smem) ====
__device__ void dev_gemm_ks(const float* A, const float* B, float* C,
                            int bid, char* smem) {
  float* As = (float*)smem;            // [32][68]
  float* Bs = As + 32 * 68;            // [32][128]
  int t = threadIdx.x;
  int c0 = (t & 31) * 4;
  int r0 = (t >> 5) * 8;
  int row0 = (bid >> 3) * 64;
  int kbeg = (bid & 7) * 128;
  int kend = kbeg + 128;
  int lr = t >> 2, lkb = (t & 3) * 8;
  float acc[8][4] = {};
  for (int k0 = kbeg; k0 < kend; k0 += 32) {
    __syncthreads();
    for (int idx = t * 4; idx < 32 * 128; idx += 1024)
      *(float4*)&Bs[(idx >> 7) * 128 + (idx & 127)] = *(const float4*)&B[(size_t)k0 * 128 + idx];
    {
      const float* ap = A + (size_t)(row0 + lr) * NSP + k0 + lkb;
      float4 v0 = *(const float4*)ap;
      float4 v1 = *(const float4*)(ap + 4);
      As[(lkb + 0) * 68 + lr] = v0.x; As[(lkb + 1) * 68 + lr] = v0.y;
      As[(lkb + 2) * 68 + lr] = v0.z; As[(lkb + 3) * 68 + lr] = v0.w;
      As[(lkb + 4) * 68 + lr] = v1.x; As[(lkb + 5) * 68 + lr] = v1.y;
      As[(lkb + 6) * 68 + lr] = v1.z; As[(lkb + 7) * 68 + lr] = v1.w;
    }
    __syncthreads();
    #pragma unroll 2
    for (int k = 0; k < 32; ++k) {
      float4 b4 = *(float4*)&Bs[k * 128 + c0];
      float4 a0 = *(float4*)&As[k * 68 + r0];
      float4 a1 = *(float4*)&As[k * 68 + r0 + 4];
      float av[8] = {a0.x, a0.y, a0.z, a0.w, a1.x, a1.y, a1.z, a1.w};
      float bv[4] = {b4.x, b4.y, b4.z, b4.w};
      #pragma unroll
      for (int r = 0; r < 8; ++r)
        #pragma unroll
        for (int c = 0; c < 4; ++c)
          acc[r][c] = fmaf(av[r], bv[c], acc[r][c]);
    }
  }
  #pragma unroll
  for (int r = 0; r < 8; ++r)
    #pragma unroll
    for (int c = 0; c < 4; ++c)
      atomicAdd(&C[(size_t)(row0 + r0 + r) * 128 + c0 + c], acc[r][c]);
}

// ============================ fused dispatches ===================================
__global__ __launch_bounds__(256) void k_za(P p) {        // scan_a | mgemm_pre
  __shared__ __align__(16) char smem[31744];
  int b = blockIdx.x;
  if (b < 256) dev_scan_a(p, b, smem);
  else dev_mgemm((const void*)p.xb, 1, 224, p.WTpre, 224, 224,
                 p.preB, nullptr, nullptr, (void*)p.bufA, 0,
                 S_A(p), S_A(p) + 128, b - 256, smem);
}
__global__ __launch_bounds__(256) void k_zb(P p) {        // scan_c2 | pool2
  __shared__ __align__(16) char smem[4096];
  int b = blockIdx.x;
  if (b < 256) dev_scan_c2(p, b, smem);
  else dev_pool2(p, b - 256, smem);
}
__global__ __launch_bounds__(256) void k_zc(P p) {        // scatter | rstatsHW
  __shared__ __align__(16) char smem[1024];
  int b = blockIdx.x;
  if (b < NE / 256) dev_scatter(p, b);
  else dev_rstats(p.bufA, nullptr, p.invM1, S_M1(p), S_M1(p) + 128, HW,
                  S_A(p), S_A(p) + 128, (float)HW, 0, b - NE / 256, 512, smem);
}
__global__ __launch_bounds__(256) void k_z8(P p) {        // rstatsG1(->xn1) | prepwM1
  __shared__ __align__(16) char smem[8192];
  int b = blockIdx.x;
  if (b < 16) dev_rstats(p.spA, p.xn1, p.invG1, S_G1(p), S_G1(p) + 128, NSP,
                         nullptr, nullptr, 1.f, 0, b, 16, smem);
  else dev_prepw(S_M1(p), S_M1(p) + 128, (float)HW, p.m1W, nullptr,
                 S_A(p), S_A(p) + 128, (float)HW,
                 nullptr, p.WTm1, p.cvM1, p.bpM1, smem);
}
__global__ __launch_bounds__(256) void k_z9(P p) {        // anormZ1 | prepwG1 | mgemmM1
  __shared__ __align__(16) char smem[31744];
  int b = blockIdx.x;
  if (b < 128) dev_gemm_ks(p.A_norm, p.xn1, p.z1p, b, smem);
  else if (b < 129) dev_prepw(S_G1(p), S_G1(p) + 128, (float)NSP, p.g1W, p.g1b,
                              nullptr, nullptr, 1.f, p.WppG1, nullptr, p.cvG1, p.bpG1, smem);
  else dev_mgemm((const void*)p.bufA, 0, 128, p.WTm1, 128, 128,
                 p.bpM1, p.cvM1, p.invM1, (void*)p.xwB, 1,
                 nullptr, nullptr, b - 129, smem);
}
__global__ __launch_bounds__(256) void k_z10(P p) {       // g1tail | agg1_cs
  int b = blockIdx.x;
  if (b < 64) dev_gemm_tail(p.z1p, p.WppG1, p.bpG1, p.rsums, p.spDp, b);
  else dev_agg_cs(p, p.xwB, p.m1b, (void*)p.bufN, 1, p.rowss, b - 64);
}
__global__ __launch_bounds__(256) void k_z10b(P p) {      // phaseB | rstatsG2(->xn2)
  __shared__ __align__(16) char smem[1024];
  int b = blockIdx.x;
  if (b < 512) dev_phaseB(p, b, 512, smem);
  else dev_rstats(p.spDp, p.xn2, p.invG2, S_G2(p), S_G2(p) + 128, NSP,
                  nullptr, nullptr, 1.f, 1, b - 512, 16, smem);
}
__global__ __launch_bounds__(256) void k_z11(P p) {       // prepwM2 | prepwG2
  __shared__ __align__(16) char smem[8192];
  int b = blockIdx.x;
  if (b < 1) dev_prepw(S_M2(p), S_M2(p) + 128, (float)HW, p.m2W, nullptr,
                       nullptr, nullptr, 1.f, nullptr, p.WTm2, p.cvM2, p.bpM2, smem);
  else dev_prepw(S_G2(p), S_G2(p) + 128, (float)NSP, p.g2W, p.g2b,
                 nullptr, nullptr, 1.f, p.WppG2, nullptr, p.cvG2, p.bpG2, smem);
}
__global__ __launch_bounds__(256) void k_z12(P p) {       // anormZ2 | mgemmM2
  __shared__ __align__(16) char smem[31744];
  int b = blockIdx.x;
  if (b < 128) dev_gemm_ks(p.A_norm, p.xn2, p.z2p, b, smem);
  else dev_mgemm((const void*)p.bufN, 1, 128, p.WTm2, 128, 128,
                 p.bpM2, p.cvM2, p.invM2, (void*)p.xwB, 1,
                 nullptr, nullptr, b - 128, smem);
}
__global__ __launch_bounds__(256) void k_z13(P p) {       // g2tail | agg2_cs
  int b = blockIdx.x;
  if (b < 64) dev_gemm_tail(p.z2p, p.WppG2, p.bpG2, p.rsums, p.spHp, b);
  else dev_agg_cs(p, p.xwB, p.m2b, (void*)p.bufB, 0, nullptr, b - 64);
}

// ============ final: (m2 + leaky(H1p[seg])) @ out_W + out_b -> softmax ==========
__global__ __launch_bounds__(256) void k_final(P p) {
  __shared__ float rb[16][132];
  __shared__ float WL[128 * 16];
  int t = threadIdx.x;
  int row0 = blockIdx.x * 16;
  for (int idx = t; idx < 128 * NCLS; idx += 256) WL[idx] = p.oW[idx];
  for (int idx = t; idx < 16 * 128; idx += 256) {
    int r = idx >> 7, d = idx & 127;
    int row = row0 + r;
    float h = p.spHp[(size_t)p.seg[row] * 128 + d];
    h = (h >= 0.f) ? h : LSLOPE * h;
    rb[r][d] = p.bufB[(size_t)row * 128 + d] + h;
  }
  __syncthreads();
  int c = t & 15, r = t >> 4;
  float acc = p.ob[c];
  #pragma unroll 8
  for (int d = 0; d < 128; ++d) acc = fmaf(rb[r][d], WL[d * 16 + c], acc);
  float mx = acc;
  #pragma unroll
  for (int o = 1; o < 16; o <<= 1) mx = fmaxf(mx, __shfl_xor(mx, o));
  float e = expf(acc - mx);
  float s = e;
  #pragma unroll
  for (int o = 1; o < 16; o <<= 1) s += __shfl_xor(s, o);
  p.outp[(size_t)(row0 + r) * NCLS + c] = e / s;
}

// =================================================================================
extern "C" void kernel_launch(void* const* d_in, const int* in_sizes, int n_in,
                              void* d_out, int out_size, void* d_ws, size_t ws_size,
                              hipStream_t stream) {
  P p;
  p.x      = (const float*)d_in[0];
  p.Q      = (const float*)d_in[1];
  p.A_norm = (const float*)d_in[2];
  p.e_src  = (const int*)d_in[3];
  p.e_dst  = (const int*)d_in[3] + NE;
  p.preW = (const float*)d_in[4];  p.preB = (const float*)d_in[5];
  p.g1W  = (const float*)d_in[6];  p.g1b  = (const float*)d_in[7];
  p.g2W  = (const float*)d_in[8];  p.g2b  = (const float*)d_in[9];
  p.m1W  = (const float*)d_in[10]; p.m1b  = (const float*)d_in[11];
  p.m2W  = (const float*)d_in[12]; p.m2b  = (const float*)d_in[13];
  p.oW   = (const float*)d_in[14]; p.ob   = (const float*)d_in[15];
  p.outp = (float*)d_out;

  char* ws = (char*)d_ws;
  size_t o = 0;
  auto alloc = [&](size_t bytes) { size_t r = o; o = (o + bytes + 255) & ~255ULL; return r; };
  size_t bufA_o   = alloc((size_t)HW * 128 * 4);
  size_t bufB_o   = alloc((size_t)HW * 128 * 4);
  // ---- zero group ----
  size_t cntd_o   = alloc((size_t)HW * 4);
  size_t cntinv_o = alloc((size_t)NSP * 4);
  size_t stats_o  = alloc(5 * 256 * 4);
  size_t z1p_o    = alloc((size_t)NSP * 128 * 4);
  size_t z2p_o    = alloc((size_t)NSP * 128 * 4);
  size_t rowss_o  = alloc((size_t)HW * 4);
  size_t zero_end = o;
  // ---- end zero group ----
  size_t spDp_o   = alloc((size_t)NSP * 128 * 4);
  size_t spHp_o   = alloc((size_t)NSP * 128 * 4);
  size_t seg_o    = alloc((size_t)HW * 4);
  size_t seginv_o = alloc((size_t)HW * 4);
  size_t off_o    = alloc((size_t)(HW + 1) * 4);
  size_t cur_o    = alloc((size_t)HW * 4);
  size_t dinv_o   = alloc((size_t)HW * 4);
  size_t e2_o     = alloc((size_t)NE * 8);
  size_t bsum_o   = alloc(256 * 4);
  size_t spA_o    = alloc((size_t)NSP * 128 * 4);
  size_t xn1_o    = alloc((size_t)NSP * 128 * 4);
  size_t xn2_o    = alloc((size_t)NSP * 128 * 4);
  size_t rsums_o  = alloc((size_t)NSP * 4);
  size_t invM2_o  = alloc((size_t)HW * 4);
  size_t WppG1_o  = alloc(128 * 128 * 4);
  size_t WppG2_o  = alloc(128 * 128 * 4);
  size_t WTm1_o   = alloc(128 * 128 * 2);
  size_t WTm2_o   = alloc(128 * 128 * 2);
  size_t WTpre_o  = alloc(128 * 224 * 2);
  size_t cvG1_o = alloc(512), bpG1_o = alloc(512);
  size_t cvG2_o = alloc(512), bpG2_o = alloc(512);
  size_t cvM1_o = alloc(512), bpM1_o = alloc(512);
  size_t cvM2_o = alloc(512), bpM2_o = alloc(512);
  size_t invG1_o  = alloc((size_t)NSP * 4);
  size_t invG2_o  = alloc((size_t)NSP * 4);
  size_t invM1_o  = alloc((size_t)HW * 4);
  size_t xb_o     = alloc((size_t)HW * 224 * 2);
  size_t xwB_o    = alloc((size_t)HW * 128 * 2);
  size_t bufN_o   = alloc((size_t)HW * 128 * 2);
  if (o > ws_size) return;

  p.bufA  = (float*)(ws + bufA_o);
  p.bufB  = (float*)(ws + bufB_o);
  p.cntd  = (int*)(ws + cntd_o);
  p.cntinv= (int*)(ws + cntinv_o);
  p.stats = (float*)(ws + stats_o);
  p.z1p   = (float*)(ws + z1p_o);
  p.z2p   = (float*)(ws + z2p_o);
  p.rowss = (float*)(ws + rowss_o);
  p.spDp  = (float*)(ws + spDp_o);
  p.spHp  = (float*)(ws + spHp_o);
  p.seg   = (int*)(ws + seg_o);
  p.seginv= (int*)(ws + seginv_o);
  p.offp  = (int*)(ws + off_o);
  p.cur   = (int*)(ws + cur_o);
  p.dinv  = (float*)(ws + dinv_o);
  p.e2    = (int2*)(ws + e2_o);
  p.bsum  = (int*)(ws + bsum_o);
  p.spA   = (float*)(ws + spA_o);
  p.xn1   = (float*)(ws + xn1_o);
  p.xn2   = (float*)(ws + xn2_o);
  p.rsums = (float*)(ws + rsums_o);
  p.invM2 = (float*)(ws + invM2_o);
  p.WppG1 = (float*)(ws + WppG1_o);
  p.WppG2 = (float*)(ws + WppG2_o);
  p.WTm1  = (u16*)(ws + WTm1_o);
  p.WTm2  = (u16*)(ws + WTm2_o);
  p.WTpre = (u16*)(ws + WTpre_o);
  p.cvG1 = (float*)(ws + cvG1_o); p.bpG1 = (float*)(ws + bpG1_o);
  p.cvG2 = (float*)(ws + cvG2_o); p.bpG2 = (float*)(ws + bpG2_o);
  p.cvM1 = (float*)(ws + cvM1_o); p.bpM1 = (float*)(ws + bpM1_o);
  p.cvM2 = (float*)(ws + cvM2_o); p.bpM2 = (float*)(ws + bpM2_o);
  p.invG1 = (float*)(ws + invG1_o);
  p.invG2 = (float*)(ws + invG2_o);
  p.invM1 = (float*)(ws + invM1_o);
  p.xb   = (u16*)(ws + xb_o);
  p.xwB  = (u16*)(ws + xwB_o);
  p.bufN = (u16*)(ws + bufN_o);

  hipMemsetAsync(ws + cntd_o, 0, zero_end - cntd_o, stream);

  hipLaunchKernelGGL(k_setup, dim3(NQB + NDB + CXB + CWB + RSB), dim3(256), 0, stream, p);
  hipLaunchKernelGGL(k_za,    dim3(256 + HW / 64), dim3(256), 0, stream, p);
  hipLaunchKernelGGL(k_zb,    dim3(256 + NSP), dim3(256), 0, stream, p);
  hipLaunchKernelGGL(k_zc,    dim3(NE / 256 + 512), dim3(256), 0, stream, p);
  hipLaunchKernelGGL(k_z8,    dim3(17), dim3(256), 0, stream, p);
  hipLaunchKernelGGL(k_z9,    dim3(129 + HW / 64), dim3(256), 0, stream, p);
  hipLaunchKernelGGL(k_z10,   dim3(64 + 2048), dim3(256), 0, stream, p);
  hipLaunchKernelGGL(k_z10b,  dim3(512 + 16), dim3(256), 0, stream, p);
  hipLaunchKernelGGL(k_z11,   dim3(2), dim3(256), 0, stream, p);
  hipLaunchKernelGGL(k_z12,   dim3(128 + HW / 64), dim3(256), 0, stream, p);
  hipLaunchKernelGGL(k_z13,   dim3(64 + 2048), dim3(256), 0, stream, p);
  hipLaunchKernelGGL(k_final, dim3(HW / 16), dim3(256), 0, stream, p);
}

// Round 11
// 447.693 us; speedup vs baseline: 1.7731x; 1.7731x over previous
//
#include <hip/hip_runtime.h>

#define HW 65536
#define NSP 1024
#define NE 524288
#define NCLS 16
#define BN_EPS 1e-5f
#define LSLOPE 0.01f

typedef unsigned short u16;
typedef short s16x8 __attribute__((ext_vector_type(8)));
typedef u16 u16x8 __attribute__((ext_vector_type(8)));
typedef u16 u16x4 __attribute__((ext_vector_type(4)));
typedef float f32x4 __attribute__((ext_vector_type(4)));

__device__ inline u16 f2b(float x) {            // f32 -> bf16 RNE
  unsigned int u = __float_as_uint(x);
  unsigned int r = ((u >> 16) & 1u) + 0x7FFFu;
  return (u16)((u + r) >> 16);
}
__device__ inline float b2f(u16 u) { return __uint_as_float(((unsigned int)u) << 16); }

struct P {
  const float *x, *Q, *A_norm;
  const int *e_src, *e_dst;
  const float *preW, *preB;
  const float *g1W, *g1b, *g2W, *g2b;
  const float *m1W, *m1b, *m2W, *m2b;
  const float *oW, *ob;
  float *outp;
  float *bufA, *bufB;
  int *cntd, *cntinv;
  float *stats;                       // 5 pairs of (sum[128], sumsq[128])
  float *spDp, *spHp;
  int *seg, *seginv, *offp, *cur;
  float *dinv;
  int2 *e2;
  int *bsum;
  float *spA;
  float *xn1, *xn2, *z1p, *z2p, *rsums;
  float *WppG1, *WppG2;
  u16 *WTm1, *WTm2, *WTpre;
  float *cvG1, *bpG1, *cvG2, *bpG2, *cvM1, *bpM1, *cvM2, *bpM2;
  float *invG1, *invG2, *invM1;
  u16 *xb, *xwB, *bufN;
};

#define S_A(p)  ((p).stats + 0*256)
#define S_G1(p) ((p).stats + 1*256)
#define S_G2(p) ((p).stats + 2*256)
#define S_M1(p) ((p).stats + 3*256)
#define S_M2(p) ((p).stats + 4*256)

#define NQB 4096
#define NDB (NE / 256)
#define CXB (HW * 56 / 256)
#define CWB 112
#define RSB 256

// == k_setup: seg/seg_inv (early-exit one-hot scan) + degree + x->bf16 + preW->bf16T + A rowsums ==
__global__ __launch_bounds__(256) void k_setup(P p) {
  int b = blockIdx.x, t = threadIdx.x;
  int wv = t >> 6, lane = t & 63;
  if (b < NQB) {
    #pragma unroll
    for (int rr = 0; rr < 4; ++rr) {
      int row = (b * 4 + wv) * 4 + rr;
      const float4* qrow = (const float4*)(p.Q + (size_t)row * NSP);
      for (int c = 0; c < 4; ++c) {
        float4 v = qrow[c * 64 + lane];
        int hit = (v.x > 0.5f) || (v.y > 0.5f) || (v.z > 0.5f) || (v.w > 0.5f);
        unsigned long long m = __ballot(hit);
        if (m) {
          int L = (int)__ffsll((unsigned long long)m) - 1;
          if (lane == L) {
            int comp = (v.x > 0.5f) ? 0 : (v.y > 0.5f) ? 1 : (v.z > 0.5f) ? 2 : 3;
            int s = c * 256 + lane * 4 + comp;
            p.seg[row] = s;
            int pos = atomicAdd(&p.cntinv[s], 1);
            p.seginv[s * 64 + pos] = row;
          }
          break;
        }
      }
    }
  } else if (b < NQB + NDB) {
    int e = (b - NQB) * 256 + t;
    if (e < NE) atomicAdd(&p.cntd[p.e_dst[e]], 1);
  } else if (b < NQB + NDB + CXB) {
    int g = (b - NQB - NDB) * 256 + t;
    int row = g / 56, qd = g - row * 56;
    int k0 = qd * 4;
    u16x4 o;
    if (k0 < 200) {
      float4 v = *(const float4*)&p.x[(size_t)row * 200 + k0];
      o[0] = f2b(v.x); o[1] = f2b(v.y); o[2] = f2b(v.z); o[3] = f2b(v.w);
    } else { o[0] = 0; o[1] = 0; o[2] = 0; o[3] = 0; }
    *(u16x4*)&p.xb[(size_t)row * 224 + k0] = o;
  } else if (b < NQB + NDB + CXB + CWB) {
    int g = (b - NQB - NDB - CXB) * 256 + t;
    if (g < 128 * 224) {
      int n = g / 224, k = g - n * 224;
      p.WTpre[g] = (k < 200) ? f2b(p.preW[(size_t)k * 128 + n]) : (u16)0;
    }
  } else {
    int row = (b - NQB - NDB - CXB - CWB) * 4 + wv;
    const float4* ar = (const float4*)(p.A_norm + (size_t)row * NSP);
    float s = 0.f;
    #pragma unroll
    for (int c = 0; c < 4; ++c) {
      float4 v = ar[c * 64 + lane];
      s += v.x + v.y + v.z + v.w;
    }
    #pragma unroll
    for (int o = 1; o < 64; o <<= 1) s += __shfl_xor(s, o);
    if (lane == 0) p.rsums[row] = s;
  }
}

// =========================== device: scan_a =====================================
__device__ void dev_scan_a(P& p, int b, char* smem) {
  int* s = (int*)smem;
  int t = threadIdx.x;
  int i = b * 256 + t;
  int v = p.cntd[i];
  s[t] = v; __syncthreads();
  for (int o = 1; o < 256; o <<= 1) {
    int x = (t >= o) ? s[t - o] : 0;
    __syncthreads();
    s[t] += x;
    __syncthreads();
  }
  p.offp[i] = s[t] - v;
  if (t == 255) p.bsum[b] = s[t];
}

// ================== device: scan_c2 (merged scan_b + scan_c) ====================
__device__ void dev_scan_c2(P& p, int b, char* smem) {
  int* w4 = (int*)smem;
  int t = threadIdx.x;
  int v = (t < b) ? p.bsum[t] : 0;
  #pragma unroll
  for (int o = 1; o < 64; o <<= 1) v += __shfl_xor(v, o);
  if ((t & 63) == 0) w4[t >> 6] = v;
  __syncthreads();
  int base = w4[0] + w4[1] + w4[2] + w4[3];
  int i = b * 256 + t;
  int ov = p.offp[i] + base;
  p.offp[i] = ov;
  p.cur[i] = ov;
  p.dinv[i] = rsqrtf((float)p.cntd[i] + 1.0f);
  if (i == 0) p.offp[HW] = NE;
}

// ============================ device: scatter ====================================
__device__ void dev_scatter(P& p, int b) {
  int e = b * 256 + threadIdx.x;
  if (e < NE) {
    int d = p.e_dst[e], s = p.e_src[e];
    float w = p.dinv[d] * p.dinv[s];
    int pos = atomicAdd(&p.cur[d], 1);
    p.e2[pos] = make_int2(s, __float_as_int(w));
  }
}

// ====================== device: MFMA bf16 GEMM (needs 31744B smem) ===============
__device__ void dev_mgemm(const void* Ap, int a_bf16, int lda,
                          const u16* WT, int ldb, int K,
                          const float* bias, const float* cvec, const float* invn,
                          void* Cp, int c_bf16,
                          float* sums, float* sumsq, int bid, char* smem) {
  u16* As = (u16*)smem;                 // [2][64][40]
  u16* Bs = (u16*)(smem + 10240);       // [2][128][40]
  float* lsum = (float*)(smem + 30720);
  float* lssq = lsum + 128;
  int t = threadIdx.x;
  if (sums && t < 128) { lsum[t] = 0.f; lssq[t] = 0.f; }
  int row0 = bid * 64;
  int ar = t >> 2, ak = (t & 3) * 8;
  u16x8 aReg; u16x8 bReg[2];

  auto loadRegs = [&](int k0) {
    if (a_bf16) {
      aReg = *(const u16x8*)((const u16*)Ap + (size_t)(row0 + ar) * lda + k0 + ak);
    } else {
      const float* ap = (const float*)Ap + (size_t)(row0 + ar) * lda + k0 + ak;
      float4 f0 = *(const float4*)ap;
      float4 f1 = *(const float4*)(ap + 4);
      u16x8 v;
      v[0] = f2b(f0.x); v[1] = f2b(f0.y); v[2] = f2b(f0.z); v[3] = f2b(f0.w);
      v[4] = f2b(f1.x); v[5] = f2b(f1.y); v[6] = f2b(f1.z); v[7] = f2b(f1.w);
      aReg = v;
    }
    #pragma unroll
    for (int it = 0; it < 2; ++it) {
      int slot = t + it * 256;
      int bn = slot >> 2, kg = (slot & 3) * 8;
      bReg[it] = *(const u16x8*)(WT + (size_t)bn * ldb + k0 + kg);
    }
  };
  auto dsWrite = [&](int bq) {
    *(u16x8*)&As[(bq * 64 + ar) * 40 + ak] = aReg;
    #pragma unroll
    for (int it = 0; it < 2; ++it) {
      int slot = t + it * 256;
      int bn = slot >> 2, kg = (slot & 3) * 8;
      *(u16x8*)&Bs[(bq * 128 + bn) * 40 + kg] = bReg[it];
    }
  };

  int lane = t & 63, wvv = t >> 6;
  int m0 = (wvv >> 1) * 32, n0 = (wvv & 1) * 64;
  int fr = lane & 15, fk = (lane >> 4) * 8;
  f32x4 acc[2][4];
  #pragma unroll
  for (int mt = 0; mt < 2; ++mt)
    #pragma unroll
    for (int nt = 0; nt < 4; ++nt)
      acc[mt][nt] = (f32x4){0.f, 0.f, 0.f, 0.f};

  int nch = K >> 5;
  loadRegs(0);
  int cur = 0;
  for (int ch = 0; ch < nch; ++ch) {
    dsWrite(cur);
    __syncthreads();
    if (ch + 1 < nch) loadRegs((ch + 1) << 5);
    s16x8 afr0 = *(const s16x8*)&As[(cur * 64 + m0 + fr) * 40 + fk];
    s16x8 afr1 = *(const s16x8*)&As[(cur * 64 + m0 + 16 + fr) * 40 + fk];
    s16x8 bfr[4];
    #pragma unroll
    for (int nt = 0; nt < 4; ++nt)
      bfr[nt] = *(const s16x8*)&Bs[(cur * 128 + n0 + nt * 16 + fr) * 40 + fk];
    #pragma unroll
    for (int nt = 0; nt < 4; ++nt) {
      acc[0][nt] = __builtin_amdgcn_mfma_f32_16x16x32_bf16(afr0, bfr[nt], acc[0][nt], 0, 0, 0);
      acc[1][nt] = __builtin_amdgcn_mfma_f32_16x16x32_bf16(afr1, bfr[nt], acc[1][nt], 0, 0, 0);
    }
    cur ^= 1;
  }

  float bb4[4], cv4[4];
  #pragma unroll
  for (int nt = 0; nt < 4; ++nt) {
    int c = n0 + nt * 16 + fr;
    bb4[nt] = bias ? bias[c] : 0.f;
    cv4[nt] = cvec ? cvec[c] : 0.f;
  }
  int rg = lane >> 4;
  float cs4[4] = {}, cq4[4] = {};
  #pragma unroll
  for (int mt = 0; mt < 2; ++mt) {
    int rbase = row0 + m0 + mt * 16 + rg * 4;
    float inr[4];
    #pragma unroll
    for (int j = 0; j < 4; ++j) inr[j] = invn ? invn[rbase + j] : 1.f;
    #pragma unroll
    for (int nt = 0; nt < 4; ++nt) {
      int c = n0 + nt * 16 + fr;
      #pragma unroll
      for (int j = 0; j < 4; ++j) {
        float xv = inr[j] * (acc[mt][nt][j] - cv4[nt]) + bb4[nt];
        if (sums) { cs4[nt] += xv; cq4[nt] += xv * xv; }
        if (c_bf16) ((u16*)Cp)[(size_t)(rbase + j) * 128 + c] = f2b(xv);
        else        ((float*)Cp)[(size_t)(rbase + j) * 128 + c] = xv;
      }
    }
  }
  if (sums) {
    __syncthreads();
    #pragma unroll
    for (int nt = 0; nt < 4; ++nt) {
      int c = n0 + nt * 16 + fr;
      atomicAdd(&lsum[c], cs4[nt]);
      atomicAdd(&lssq[c], cq4[nt]);
    }
    __syncthreads();
    if (t < 128) { atomicAdd(&sums[t], lsum[t]); atomicAdd(&sumsq[t], lssq[t]); }
  }
}

// =================== device: superpixel mean-pool (4096B smem) ==================
__device__ void dev_pool2(P& p, int sp, char* smem) {
  float4* part = (float4*)smem;   // [8][32]
  int t = threadIdx.x;
  int l32 = t & 31, g = t >> 5;
  int cnt = p.cntinv[sp];
  const float4* y4 = (const float4*)p.bufA;
  const int* lst = p.seginv + sp * 64;
  float4 acc = make_float4(0.f, 0.f, 0.f, 0.f);
  int r = g;
  for (; r + 8 < cnt; r += 16) {
    int i0 = lst[r], i1 = lst[r + 8];
    float4 a = y4[(size_t)i0 * 32 + l32];
    float4 b = y4[(size_t)i1 * 32 + l32];
    acc.x += a.x + b.x; acc.y += a.y + b.y;
    acc.z += a.z + b.z; acc.w += a.w + b.w;
  }
  for (; r < cnt; r += 8) {
    float4 a = y4[(size_t)lst[r] * 32 + l32];
    acc.x += a.x; acc.y += a.y; acc.z += a.z; acc.w += a.w;
  }
  part[g * 32 + l32] = acc;
  __syncthreads();
  if (g == 0) {
    float4 s = part[l32];
    #pragma unroll
    for (int q = 1; q < 8; ++q) {
      float4 pp = part[q * 32 + l32];
      s.x += pp.x; s.y += pp.y; s.z += pp.z; s.w += pp.w;
    }
    int d0 = l32 * 4;
    const float* sAs = S_A(p);
    const float* sAq = S_A(p) + 128;
    float4 ss = *(const float4*)&sAs[d0];
    float4 sq = *(const float4*)&sAq[d0];
    float inv = 1.0f / (float)cnt;
    float4 o;
    float m, rs;
    m = ss.x / HW; rs = rsqrtf(sq.x / HW - m * m + BN_EPS); o.x = (s.x * inv - m) * rs;
    m = ss.y / HW; rs = rsqrtf(sq.y / HW - m * m + BN_EPS); o.y = (s.y * inv - m) * rs;
    m = ss.z / HW; rs = rsqrtf(sq.z / HW - m * m + BN_EPS); o.z = (s.z * inv - m) * rs;
    m = ss.w / HW; rs = rsqrtf(sq.w / HW - m * m + BN_EPS); o.w = (s.w * inv - m) * rs;
    *(float4*)&p.spA[sp * 128 + d0] = o;
  }
}

// == device: row inv-norms + col-stats of normalized; optional normalized write ==
__device__ void dev_rstats(const float* in, float* norm_out, float* invn,
                           float* sums, float* sumsq, int M,
                           const float* preS, const float* preQ, float precnt,
                           int leaky_in, int bid, int nb, char* smem) {
  float* lsum = (float*)smem;
  float* lssq = lsum + 128;
  int t = threadIdx.x;
  if (t < 128) { lsum[t] = 0.f; lssq[t] = 0.f; }
  __syncthreads();
  int wid = t >> 6, lane = t & 63, d0 = lane * 2;
  float m0 = 0.f, m1 = 0.f, r0 = 1.f, r1 = 1.f;
  if (preS) {
    m0 = preS[d0] / precnt;
    r0 = rsqrtf(preQ[d0] / precnt - m0 * m0 + BN_EPS);
    m1 = preS[d0 + 1] / precnt;
    r1 = rsqrtf(preQ[d0 + 1] / precnt - m1 * m1 + BN_EPS);
  }
  float cs0 = 0.f, cs1 = 0.f, cq0 = 0.f, cq1 = 0.f;
  for (int row = bid * 4 + wid; row < M; row += nb * 4) {
    float2 v = *(const float2*)(in + (size_t)row * 128 + d0);
    v.x = (v.x - m0) * r0;
    v.y = (v.y - m1) * r1;
    if (leaky_in) {
      v.x = (v.x >= 0.f) ? v.x : LSLOPE * v.x;
      v.y = (v.y >= 0.f) ? v.y : LSLOPE * v.y;
    }
    float ss = v.x * v.x + v.y * v.y;
    #pragma unroll
    for (int o = 1; o < 64; o <<= 1) ss += __shfl_xor(ss, o);
    float sc = 1.0f / fmaxf(sqrtf(ss), 1e-12f);
    if (lane == 0) invn[row] = sc;
    float nx = v.x * sc, ny = v.y * sc;
    if (norm_out) *(float2*)(norm_out + (size_t)row * 128 + d0) = make_float2(nx, ny);
    cs0 += nx; cs1 += ny; cq0 += nx * nx; cq1 += ny * ny;
  }
  atomicAdd(&lsum[d0], cs0); atomicAdd(&lsum[d0 + 1], cs1);
  atomicAdd(&lssq[d0], cq0); atomicAdd(&lssq[d0 + 1], cq1);
  __syncthreads();
  if (t < 128) { atomicAdd(&sums[t], lsum[t]); atomicAdd(&sumsq[t], lssq[t]); }
}

// ====== device: fold BN(s) into W -> optional Wpp(f32) / WT(bf16 T) (8192B) =====
__device__ void dev_prepw(const float* sums, const float* sumsq, float cnt,
                          const float* W, const float* base,
                          const float* preS, const float* preQ, float precnt,
                          float* Wpp, u16* WT, float* cvec, float* bp, char* smem) {
  float* redc = (float*)smem;            // [8][128]
  float* redb = redc + 1024;
  int t = threadIdx.x;
  int kq = (t & 31) * 4, jg = t >> 5;
  float cx = 0.f, cy = 0.f, cz = 0.f, cw = 0.f;
  float bx = 0.f, by = 0.f, bz = 0.f, bw = 0.f;
  for (int j = jg; j < 128; j += 8) {
    float m2 = sums[j] / cnt;
    float rs2 = rsqrtf(sumsq[j] / cnt - m2 * m2 + BN_EPS);
    float mA = 0.f, rsA = 1.f;
    if (preS) {
      mA = preS[j] / precnt;
      rsA = rsqrtf(preQ[j] / precnt - mA * mA + BN_EPS);
    }
    float4 w = *(const float4*)&W[j * 128 + kq];
    float sA = rsA * rs2;
    float4 wpp = make_float4(sA * w.x, sA * w.y, sA * w.z, sA * w.w);
    if (Wpp) *(float4*)&Wpp[j * 128 + kq] = wpp;
    if (WT) {
      WT[(size_t)(kq + 0) * 128 + j] = f2b(wpp.x);
      WT[(size_t)(kq + 1) * 128 + j] = f2b(wpp.y);
      WT[(size_t)(kq + 2) * 128 + j] = f2b(wpp.z);
      WT[(size_t)(kq + 3) * 128 + j] = f2b(wpp.w);
    }
    cx = fmaf(mA, wpp.x, cx); cy = fmaf(mA, wpp.y, cy);
    cz = fmaf(mA, wpp.z, cz); cw = fmaf(mA, wpp.w, cw);
    float m2s = m2 * rs2;
    bx = fmaf(m2s, w.x, bx); by = fmaf(m2s, w.y, by);
    bz = fmaf(m2s, w.z, bz); bw = fmaf(m2s, w.w, bw);
  }
  *(float4*)&redc[jg * 128 + kq] = make_float4(cx, cy, cz, cw);
  *(float4*)&redb[jg * 128 + kq] = make_float4(bx, by, bz, bw);
  __syncthreads();
  if (t < 32) {
    int k4 = t * 4;
    float4 sc = *(float4*)&redc[k4];
    float4 sb = *(float4*)&redb[k4];
    #pragma unroll
    for (int g = 1; g < 8; ++g) {
      float4 ac = *(float4*)&redc[g * 128 + k4];
      float4 ab = *(float4*)&redb[g * 128 + k4];
      sc.x += ac.x; sc.y += ac.y; sc.z += ac.z; sc.w += ac.w;
      sb.x += ab.x; sb.y += ab.y; sb.z += ab.z; sb.w += ab.w;
    }
    *(float4*)&cvec[k4] = sc;
    float4 bs = base ? *(const float4*)&base[k4] : make_float4(0, 0, 0, 0);
    *(float4*)&bp[k4] = make_float4(bs.x - sb.x, bs.y - sb.y, bs.z - sb.z, bs.w - sb.w);
  }
}

// == device: CSR edge agg (wave-per-row, 16 gathers in flight per wave) ==========
__device__ void dev_aggb(P& p, const u16* tbl, const float* bias, void* outp,
                         int norm_bf16, float* sums, float* sumsq,
                         int bid, int nb, char* smem) {
  float* lsum = (float*)smem;
  float* lssq = lsum + 128;
  int t = threadIdx.x;
  if (norm_bf16) {
    if (t < 128) { lsum[t] = 0.f; lssq[t] = 0.f; }
    __syncthreads();
  }
  int wid = t >> 6, lane = t & 63;
  int q = lane >> 4, l16 = lane & 15, c0 = l16 * 8;
  float bb[8];
  #pragma unroll
  for (int j = 0; j < 8; ++j) bb[j] = bias[c0 + j];
  float cs[8] = {}, cq[8] = {};
  for (int i = bid * 4 + wid; i < HW; i += nb * 4) {
    int s0 = p.offp[i], s1 = p.offp[i + 1];
    float di = p.dinv[i];
    u16x8 xi = *(const u16x8*)&tbl[(size_t)i * 128 + c0];
    float acc[8] = {};
    int kk = s0 + q;
    // 4 row-gathers in flight per quarter-wave (16 per wave)
    for (; kk + 12 < s1; kk += 16) {
      int2 ea = p.e2[kk], eb = p.e2[kk + 4], ec = p.e2[kk + 8], ed = p.e2[kk + 12];
      u16x8 va = *(const u16x8*)&tbl[(size_t)ea.x * 128 + c0];
      u16x8 vb = *(const u16x8*)&tbl[(size_t)eb.x * 128 + c0];
      u16x8 vc = *(const u16x8*)&tbl[(size_t)ec.x * 128 + c0];
      u16x8 vd = *(const u16x8*)&tbl[(size_t)ed.x * 128 + c0];
      float wa = __int_as_float(ea.y), wb = __int_as_float(eb.y);
      float wc = __int_as_float(ec.y), wd = __int_as_float(ed.y);
      #pragma unroll
      for (int j = 0; j < 8; ++j) acc[j] = fmaf(wa, b2f(va[j]), acc[j]);
      #pragma unroll
      for (int j = 0; j < 8; ++j) acc[j] = fmaf(wb, b2f(vb[j]), acc[j]);
      #pragma unroll
      for (int j = 0; j < 8; ++j) acc[j] = fmaf(wc, b2f(vc[j]), acc[j]);
      #pragma unroll
      for (int j = 0; j < 8; ++j) acc[j] = fmaf(wd, b2f(vd[j]), acc[j]);
    }
    for (; kk < s1; kk += 4) {
      int2 e = p.e2[kk];
      u16x8 v = *(const u16x8*)&tbl[(size_t)e.x * 128 + c0];
      float w = __int_as_float(e.y);
      #pragma unroll
      for (int j = 0; j < 8; ++j) acc[j] = fmaf(w, b2f(v[j]), acc[j]);
    }
    #pragma unroll
    for (int j = 0; j < 8; ++j) {
      acc[j] += __shfl_xor(acc[j], 16);
      acc[j] += __shfl_xor(acc[j], 32);
    }
    float inv_deg = di * di;
    float r[8];
    #pragma unroll
    for (int j = 0; j < 8; ++j) {
      r[j] = fmaf(b2f(xi[j]), inv_deg, acc[j]) + bb[j];
      r[j] = (r[j] >= 0.f) ? r[j] : LSLOPE * r[j];
    }
    if (norm_bf16) {
      float ss = 0.f;
      #pragma unroll
      for (int j = 0; j < 8; ++j) ss += r[j] * r[j];
      ss += __shfl_xor(ss, 1); ss += __shfl_xor(ss, 2);
      ss += __shfl_xor(ss, 4); ss += __shfl_xor(ss, 8);
      float sc = 1.0f / fmaxf(sqrtf(ss), 1e-12f);
      if (q == 0) {
        u16x8 o;
        #pragma unroll
        for (int j = 0; j < 8; ++j) {
          r[j] *= sc;
          o[j] = f2b(r[j]);
          cs[j] += r[j]; cq[j] += r[j] * r[j];
        }
        *(u16x8*)&((u16*)outp)[(size_t)i * 128 + c0] = o;
      }
    } else if (q == 0) {
      float* op = (float*)outp + (size_t)i * 128 + c0;
      *(float4*)op = make_float4(r[0], r[1], r[2], r[3]);
      *(float4*)(op + 4) = make_float4(r[4], r[5], r[6], r[7]);
    }
  }
  if (norm_bf16) {
    if (q == 0) {
      #pragma unroll
      for (int j = 0; j < 8; ++j) {
        atomicAdd(&lsum[c0 + j], cs[j]);
        atomicAdd(&lssq[c0 + j], cq[j]);
      }
    }
    __syncthreads();
    if (t < 128) { atomicAdd(&sums[t], lsum[t]); atomicAdd(&sumsq[t], lssq[t]); }
  }
}

// == device: small GEMM [1024x128]@[128x128] tail: out = Z@W + rs[row]*bp[col] ===
__device__ void dev_gemm_tail(const float* Z, const float* W,
                              const float* bp, const float* rs,
                              float* out, int bid) {
  int t = threadIdx.x;
  int c = t & 127, rh = t >> 7;
  int row0 = bid * 16 + rh * 8;
  float acc[8] = {};
  const float* ip = Z + (size_t)row0 * 128;
  #pragma unroll 4
  for (int k = 0; k < 128; ++k) {
    float w = W[k * 128 + c];
    #pragma unroll
    for (int i = 0; i < 8; ++i)
      acc[i] = fmaf(ip[(size_t)i * 128 + k], w, acc[i]);
  }
  float bpc = bp[c];
  #pragma unroll
  for (int i = 0; i < 8; ++i) {
    int row = row0 + i;
    out[(size_t)row * 128 + c] = acc[i] + rs[row] * bpc;
  }
}

// ===== device: split-K GEMM A_norm[1024x1024]@Xn -> atomic out (25088B smem) ====
__device__ void dev_gemm_ks(const float* A, const float* B, float* C,
                            int bid, char* smem) {
  float* As = (float*)smem;            // [32][68]
  float* Bs = As + 32 * 68;            // [32][128]
  int t = threadIdx.x;
  int c0 = (t & 31) * 4;
  int r0 = (t >> 5) * 8;
  int row0 = (bid >> 3) * 64;
  int kbeg = (bid & 7) * 128;
  int kend = kbeg + 128;
  int lr = t >> 2, lkb = (t & 3) * 8;
  float acc[8][4] = {};
  for (int k0 = kbeg; k0 < kend; k0 += 32) {
    __syncthreads();
    for (int idx = t * 4; idx < 32 * 128; idx += 1024)
      *(float4*)&Bs[(idx >> 7) * 128 + (idx & 127)] = *(const float4*)&B[(size_t)k0 * 128 + idx];
    {
      const float* ap = A + (size_t)(row0 + lr) * NSP + k0 + lkb;
      float4 v0 = *(const float4*)ap;
      float4 v1 = *(const float4*)(ap + 4);
      As[(lkb + 0) * 68 + lr] = v0.x; As[(lkb + 1) * 68 + lr] = v0.y;
      As[(lkb + 2) * 68 + lr] = v0.z; As[(lkb + 3) * 68 + lr] = v0.w;
      As[(lkb + 4) * 68 + lr] = v1.x; As[(lkb + 5) * 68 + lr] = v1.y;
      As[(lkb + 6) * 68 + lr] = v1.z; As[(lkb + 7) * 68 + lr] = v1.w;
    }
    __syncthreads();
    #pragma unroll 2
    for (int k = 0; k < 32; ++k) {
      float4 b4 = *(float4*)&Bs[k * 128 + c0];
      float4 a0 = *(float4*)&As[k * 68 + r0];
      float4 a1 = *(float4*)&As[k * 68 + r0 + 4];
      float av[8] = {a0.x, a0.y, a0.z, a0.w, a1.x, a1.y, a1.z, a1.w};
      float bv[4] = {b4.x, b4.y, b4.z, b4.w};
      #pragma unroll
      for (int r = 0; r < 8; ++r)
        #pragma unroll
        for (int c = 0; c < 4; ++c)
          acc[r][c] = fmaf(av[r], bv[c], acc[r][c]);
    }
  }
  #pragma unroll
  for (int r = 0; r < 8; ++r)
    #pragma unroll
    for (int c = 0; c < 4; ++c)
      atomicAdd(&C[(size_t)(row0 + r0 + r) * 128 + c0 + c], acc[r][c]);
}

// ============================ fused dispatches ===================================
__global__ __launch_bounds__(256) void k_za(P p) {        // scan_a | mgemm_pre
  __shared__ __align__(16) char smem[31744];
  int b = blockIdx.x;
  if (b < 256) dev_scan_a(p, b, smem);
  else dev_mgemm((const void*)p.xb, 1, 224, p.WTpre, 224, 224,
                 p.preB, nullptr, nullptr, (void*)p.bufA, 0,
                 S_A(p), S_A(p) + 128, b - 256, smem);
}
__global__ __launch_bounds__(256) void k_zb(P p) {        // scan_c2 | pool2
  __shared__ __align__(16) char smem[4096];
  int b = blockIdx.x;
  if (b < 256) dev_scan_c2(p, b, smem);
  else dev_pool2(p, b - 256, smem);
}
__global__ __launch_bounds__(256) void k_zc(P p) {        // scatter | rstatsHW
  __shared__ __align__(16) char smem[1024];
  int b = blockIdx.x;
  if (b < NE / 256) dev_scatter(p, b);
  else dev_rstats(p.bufA, nullptr, p.invM1, S_M1(p), S_M1(p) + 128, HW,
                  S_A(p), S_A(p) + 128, (float)HW, 0, b - NE / 256, 512, smem);
}
__global__ __launch_bounds__(256) void k_z8(P p) {        // rstatsG1(->xn1) | prepwM1
  __shared__ __align__(16) char smem[8192];
  int b = blockIdx.x;
  if (b < 16) dev_rstats(p.spA, p.xn1, p.invG1, S_G1(p), S_G1(p) + 128, NSP,
                         nullptr, nullptr, 1.f, 0, b, 16, smem);
  else dev_prepw(S_M1(p), S_M1(p) + 128, (float)HW, p.m1W, nullptr,
                 S_A(p), S_A(p) + 128, (float)HW,
                 nullptr, p.WTm1, p.cvM1, p.bpM1, smem);
}
__global__ __launch_bounds__(256) void k_z9(P p) {        // anormZ1 | prepwG1 | mgemmM1
  __shared__ __align__(16) char smem[31744];
  int b = blockIdx.x;
  if (b < 128) dev_gemm_ks(p.A_norm, p.xn1, p.z1p, b, smem);
  else if (b < 129) dev_prepw(S_G1(p), S_G1(p) + 128, (float)NSP, p.g1W, p.g1b,
                              nullptr, nullptr, 1.f, p.WppG1, nullptr, p.cvG1, p.bpG1, smem);
  else dev_mgemm((const void*)p.bufA, 0, 128, p.WTm1, 128, 128,
                 p.bpM1, p.cvM1, p.invM1, (void*)p.xwB, 1,
                 nullptr, nullptr, b - 129, smem);
}
__global__ __launch_bounds__(256) void k_z10(P p) {       // g1tail | aggb1
  __shared__ __align__(16) char smem[1024];
  int b = blockIdx.x;
  if (b < 64) dev_gemm_tail(p.z1p, p.WppG1, p.bpG1, p.rsums, p.spDp, b);
  else dev_aggb(p, p.xwB, p.m1b, (void*)p.bufN, 1,
                S_M2(p), S_M2(p) + 128, b - 64, 2048, smem);
}
__global__ __launch_bounds__(256) void k_z11(P p) {       // prepwM2 | rstatsG2(->xn2)
  __shared__ __align__(16) char smem[8192];
  int b = blockIdx.x;
  if (b < 1) dev_prepw(S_M2(p), S_M2(p) + 128, (float)HW, p.m2W, nullptr,
                       nullptr, nullptr, 1.f, nullptr, p.WTm2, p.cvM2, p.bpM2, smem);
  else dev_rstats(p.spDp, p.xn2, p.invG2, S_G2(p), S_G2(p) + 128, NSP,
                  nullptr, nullptr, 1.f, 1, b - 1, 16, smem);
}
__global__ __launch_bounds__(256) void k_z12(P p) {       // anormZ2 | prepwG2 | mgemmM2
  __shared__ __align__(16) char smem[31744];
  int b = blockIdx.x;
  if (b < 128) dev_gemm_ks(p.A_norm, p.xn2, p.z2p, b, smem);
  else if (b < 129) dev_prepw(S_G2(p), S_G2(p) + 128, (float)NSP, p.g2W, p.g2b,
                              nullptr, nullptr, 1.f, p.WppG2, nullptr, p.cvG2, p.bpG2, smem);
  else dev_mgemm((const void*)p.bufN, 1, 128, p.WTm2, 128, 128,
                 p.bpM2, p.cvM2, nullptr, (void*)p.xwB, 1,
                 nullptr, nullptr, b - 129, smem);
}
__global__ __launch_bounds__(256) void k_z13(P p) {       // g2tail | aggb2
  __shared__ __align__(16) char smem[1024];
  int b = blockIdx.x;
  if (b < 64) dev_gemm_tail(p.z2p, p.WppG2, p.bpG2, p.rsums, p.spHp, b);
  else dev_aggb(p, p.xwB, p.m2b, (void*)p.bufB, 0,
                nullptr, nullptr, b - 64, 2048, smem);
}

// ============ final: (m2 + leaky(H1p[seg])) @ out_W + out_b -> softmax ==========
__global__ __launch_bounds__(256) void k_final(P p) {
  __shared__ float rb[16][132];
  __shared__ float WL[128 * 16];
  int t = threadIdx.x;
  int row0 = blockIdx.x * 16;
  for (int idx = t; idx < 128 * NCLS; idx += 256) WL[idx] = p.oW[idx];
  for (int idx = t; idx < 16 * 128; idx += 256) {
    int r = idx >> 7, d = idx & 127;
    int row = row0 + r;
    float h = p.spHp[(size_t)p.seg[row] * 128 + d];
    h = (h >= 0.f) ? h : LSLOPE * h;
    rb[r][d] = p.bufB[(size_t)row * 128 + d] + h;
  }
  __syncthreads();
  int c = t & 15, r = t >> 4;
  float acc = p.ob[c];
  #pragma unroll 8
  for (int d = 0; d < 128; ++d) acc = fmaf(rb[r][d], WL[d * 16 + c], acc);
  float mx = acc;
  #pragma unroll
  for (int o = 1; o < 16; o <<= 1) mx = fmaxf(mx, __shfl_xor(mx, o));
  float e = expf(acc - mx);
  float s = e;
  #pragma unroll
  for (int o = 1; o < 16; o <<= 1) s += __shfl_xor(s, o);
  p.outp[(size_t)(row0 + r) * NCLS + c] = e / s;
}

// =================================================================================
extern "C" void kernel_launch(void* const* d_in, const int* in_sizes, int n_in,
                              void* d_out, int out_size, void* d_ws, size_t ws_size,
                              hipStream_t stream) {
  P p;
  p.x      = (const float*)d_in[0];
  p.Q      = (const float*)d_in[1];
  p.A_norm = (const float*)d_in[2];
  p.e_src  = (const int*)d_in[3];
  p.e_dst  = (const int*)d_in[3] + NE;
  p.preW = (const float*)d_in[4];  p.preB = (const float*)d_in[5];
  p.g1W  = (const float*)d_in[6];  p.g1b  = (const float*)d_in[7];
  p.g2W  = (const float*)d_in[8];  p.g2b  = (const float*)d_in[9];
  p.m1W  = (const float*)d_in[10]; p.m1b  = (const float*)d_in[11];
  p.m2W  = (const float*)d_in[12]; p.m2b  = (const float*)d_in[13];
  p.oW   = (const float*)d_in[14]; p.ob   = (const float*)d_in[15];
  p.outp = (float*)d_out;

  char* ws = (char*)d_ws;
  size_t o = 0;
  auto alloc = [&](size_t bytes) { size_t r = o; o = (o + bytes + 255) & ~255ULL; return r; };
  size_t bufA_o   = alloc((size_t)HW * 128 * 4);
  size_t bufB_o   = alloc((size_t)HW * 128 * 4);
  // ---- zero group ----
  size_t cntd_o   = alloc((size_t)HW * 4);
  size_t cntinv_o = alloc((size_t)NSP * 4);
  size_t stats_o  = alloc(5 * 256 * 4);
  size_t z1p_o    = alloc((size_t)NSP * 128 * 4);
  size_t z2p_o    = alloc((size_t)NSP * 128 * 4);
  size_t zero_end = o;
  // ---- end zero group ----
  size_t spDp_o   = alloc((size_t)NSP * 128 * 4);
  size_t spHp_o   = alloc((size_t)NSP * 128 * 4);
  size_t seg_o    = alloc((size_t)HW * 4);
  size_t seginv_o = alloc((size_t)HW * 4);
  size_t off_o    = alloc((size_t)(HW + 1) * 4);
  size_t cur_o    = alloc((size_t)HW * 4);
  size_t dinv_o   = alloc((size_t)HW * 4);
  size_t e2_o     = alloc((size_t)NE * 8);
  size_t bsum_o   = alloc(256 * 4);
  size_t spA_o    = alloc((size_t)NSP * 128 * 4);
  size_t xn1_o    = alloc((size_t)NSP * 128 * 4);
  size_t xn2_o    = alloc((size_t)NSP * 128 * 4);
  size_t rsums_o  = alloc((size_t)NSP * 4);
  size_t WppG1_o  = alloc(128 * 128 * 4);
  size_t WppG2_o  = alloc(128 * 128 * 4);
  size_t WTm1_o   = alloc(128 * 128 * 2);
  size_t WTm2_o   = alloc(128 * 128 * 2);
  size_t WTpre_o  = alloc(128 * 224 * 2);
  size_t cvG1_o = alloc(512), bpG1_o = alloc(512);
  size_t cvG2_o = alloc(512), bpG2_o = alloc(512);
  size_t cvM1_o = alloc(512), bpM1_o = alloc(512);
  size_t cvM2_o = alloc(512), bpM2_o = alloc(512);
  size_t invG1_o  = alloc((size_t)NSP * 4);
  size_t invG2_o  = alloc((size_t)NSP * 4);
  size_t invM1_o  = alloc((size_t)HW * 4);
  size_t xb_o     = alloc((size_t)HW * 224 * 2);
  size_t xwB_o    = alloc((size_t)HW * 128 * 2);
  size_t bufN_o   = alloc((size_t)HW * 128 * 2);
  if (o > ws_size) return;

  p.bufA  = (float*)(ws + bufA_o);
  p.bufB  = (float*)(ws + bufB_o);
  p.cntd  = (int*)(ws + cntd_o);
  p.cntinv= (int*)(ws + cntinv_o);
  p.stats = (float*)(ws + stats_o);
  p.z1p   = (float*)(ws + z1p_o);
  p.z2p   = (float*)(ws + z2p_o);
  p.spDp  = (float*)(ws + spDp_o);
  p.spHp  = (float*)(ws + spHp_o);
  p.seg   = (int*)(ws + seg_o);
  p.seginv= (int*)(ws + seginv_o);
  p.offp  = (int*)(ws + off_o);
  p.cur   = (int*)(ws + cur_o);
  p.dinv  = (float*)(ws + dinv_o);
  p.e2    = (int2*)(ws + e2_o);
  p.bsum  = (int*)(ws + bsum_o);
  p.spA   = (float*)(ws + spA_o);
  p.xn1   = (float*)(ws + xn1_o);
  p.xn2   = (float*)(ws + xn2_o);
  p.rsums = (float*)(ws + rsums_o);
  p.WppG1 = (float*)(ws + WppG1_o);
  p.WppG2 = (float*)(ws + WppG2_o);
  p.WTm1  = (u16*)(ws + WTm1_o);
  p.WTm2  = (u16*)(ws + WTm2_o);
  p.WTpre = (u16*)(ws + WTpre_o);
  p.cvG1 = (float*)(ws + cvG1_o); p.bpG1 = (float*)(ws + bpG1_o);
  p.cvG2 = (float*)(ws + cvG2_o); p.bpG2 = (float*)(ws + bpG2_o);
  p.cvM1 = (float*)(ws + cvM1_o); p.bpM1 = (float*)(ws + bpM1_o);
  p.cvM2 = (float*)(ws + cvM2_o); p.bpM2 = (float*)(ws + bpM2_o);
  p.invG1 = (float*)(ws + invG1_o);
  p.invG2 = (float*)(ws + invG2_o);
  p.invM1 = (float*)(ws + invM1_o);
  p.xb   = (u16*)(ws + xb_o);
  p.xwB  = (u16*)(ws + xwB_o);
  p.bufN = (u16*)(ws + bufN_o);

  hipMemsetAsync(ws + cntd_o, 0, zero_end - cntd_o, stream);

  hipLaunchKernelGGL(k_setup, dim3(NQB + NDB + CXB + CWB + RSB), dim3(256), 0, stream, p);
  hipLaunchKernelGGL(k_za,    dim3(256 + HW / 64), dim3(256), 0, stream, p);
  hipLaunchKernelGGL(k_zb,    dim3(256 + NSP), dim3(256), 0, stream, p);
  hipLaunchKernelGGL(k_zc,    dim3(NE / 256 + 512), dim3(256), 0, stream, p);
  hipLaunchKernelGGL(k_z8,    dim3(17), dim3(256), 0, stream, p);
  hipLaunchKernelGGL(k_z9,    dim3(129 + HW / 64), dim3(256), 0, stream, p);
  hipLaunchKernelGGL(k_z10,   dim3(64 + 2048), dim3(256), 0, stream, p);
  hipLaunchKernelGGL(k_z11,   dim3(17), dim3(256), 0, stream, p);
  hipLaunchKernelGGL(k_z12,   dim3(129 + HW / 64), dim3(256), 0, stream, p);
  hipLaunchKernelGGL(k_z13,   dim3(64 + 2048), dim3(256), 0, stream, p);
  hipLaunchKernelGGL(k_final, dim3(HW / 16), dim3(256), 0, stream, p);
}

// Round 12
// 424.281 us; speedup vs baseline: 1.8710x; 1.0552x over previous
//
#include <hip/hip_runtime.h>

#define HW 65536
#define NSP 1024
#define NE 524288
#define NCLS 16
#define BN_EPS 1e-5f
#define LSLOPE 0.01f

typedef unsigned short u16;
typedef short s16x8 __attribute__((ext_vector_type(8)));
typedef u16 u16x8 __attribute__((ext_vector_type(8)));
typedef u16 u16x4 __attribute__((ext_vector_type(4)));
typedef float f32x4 __attribute__((ext_vector_type(4)));

__device__ inline u16 f2b(float x) {            // f32 -> bf16 RNE
  unsigned int u = __float_as_uint(x);
  unsigned int r = ((u >> 16) & 1u) + 0x7FFFu;
  return (u16)((u + r) >> 16);
}
__device__ inline float b2f(u16 u) { return __uint_as_float(((unsigned int)u) << 16); }

struct P {
  const float *x, *Q, *A_norm;
  const int *e_src, *e_dst;
  const float *preW, *preB;
  const float *g1W, *g1b, *g2W, *g2b;
  const float *m1W, *m1b, *m2W, *m2b;
  const float *oW, *ob;
  float *outp;
  float *bufA, *bufB;
  int *cntd, *cntinv;
  float *stats;                       // 5 pairs of (sum[128], sumsq[128])
  float *spDp, *spHp;
  int *seg, *seginv, *offp, *cur;
  float *dinv;
  int2 *e2;
  int *bsum;
  float *spA;
  float *xn1, *xn2, *z1p, *z2p, *rsums;
  float *WppG1, *WppG2;
  u16 *WTm1, *WTm2, *WTpre;
  float *cvG1, *bpG1, *cvG2, *bpG2, *cvM1, *bpM1, *cvM2, *bpM2;
  float *invG1, *invG2, *invM1;
  u16 *xb, *xwB, *bufN;
};

#define S_A(p)  ((p).stats + 0*256)
#define S_G1(p) ((p).stats + 1*256)
#define S_G2(p) ((p).stats + 2*256)
#define S_M1(p) ((p).stats + 3*256)
#define S_M2(p) ((p).stats + 4*256)

#define NQB 4096
#define NDB (NE / 256)
#define CXB (HW * 56 / 256)
#define CWB 112
#define RSB 256

// == k_setup: seg/seg_inv (early-exit one-hot scan) + degree + x->bf16 + preW->bf16T + A rowsums ==
__global__ __launch_bounds__(256) void k_setup(P p) {
  int b = blockIdx.x, t = threadIdx.x;
  int wv = t >> 6, lane = t & 63;
  if (b < NQB) {
    #pragma unroll
    for (int rr = 0; rr < 4; ++rr) {
      int row = (b * 4 + wv) * 4 + rr;
      const float4* qrow = (const float4*)(p.Q + (size_t)row * NSP);
      for (int c = 0; c < 4; ++c) {
        float4 v = qrow[c * 64 + lane];
        int hit = (v.x > 0.5f) || (v.y > 0.5f) || (v.z > 0.5f) || (v.w > 0.5f);
        unsigned long long m = __ballot(hit);
        if (m) {
          int L = (int)__ffsll((unsigned long long)m) - 1;
          if (lane == L) {
            int comp = (v.x > 0.5f) ? 0 : (v.y > 0.5f) ? 1 : (v.z > 0.5f) ? 2 : 3;
            int s = c * 256 + lane * 4 + comp;
            p.seg[row] = s;
            int pos = atomicAdd(&p.cntinv[s], 1);
            p.seginv[s * 64 + pos] = row;
          }
          break;
        }
      }
    }
  } else if (b < NQB + NDB) {
    int e = (b - NQB) * 256 + t;
    if (e < NE) atomicAdd(&p.cntd[p.e_dst[e]], 1);
  } else if (b < NQB + NDB + CXB) {
    int g = (b - NQB - NDB) * 256 + t;
    int row = g / 56, qd = g - row * 56;
    int k0 = qd * 4;
    u16x4 o;
    if (k0 < 200) {
      float4 v = *(const float4*)&p.x[(size_t)row * 200 + k0];
      o[0] = f2b(v.x); o[1] = f2b(v.y); o[2] = f2b(v.z); o[3] = f2b(v.w);
    } else { o[0] = 0; o[1] = 0; o[2] = 0; o[3] = 0; }
    *(u16x4*)&p.xb[(size_t)row * 224 + k0] = o;
  } else if (b < NQB + NDB + CXB + CWB) {
    int g = (b - NQB - NDB - CXB) * 256 + t;
    if (g < 128 * 224) {
      int n = g / 224, k = g - n * 224;
      p.WTpre[g] = (k < 200) ? f2b(p.preW[(size_t)k * 128 + n]) : (u16)0;
    }
  } else {
    int row = (b - NQB - NDB - CXB - CWB) * 4 + wv;
    const float4* ar = (const float4*)(p.A_norm + (size_t)row * NSP);
    float s = 0.f;
    #pragma unroll
    for (int c = 0; c < 4; ++c) {
      float4 v = ar[c * 64 + lane];
      s += v.x + v.y + v.z + v.w;
    }
    #pragma unroll
    for (int o = 1; o < 64; o <<= 1) s += __shfl_xor(s, o);
    if (lane == 0) p.rsums[row] = s;
  }
}

// =========================== device: scan_a =====================================
__device__ void dev_scan_a(P& p, int b, char* smem) {
  int* s = (int*)smem;
  int t = threadIdx.x;
  int i = b * 256 + t;
  int v = p.cntd[i];
  s[t] = v; __syncthreads();
  for (int o = 1; o < 256; o <<= 1) {
    int x = (t >= o) ? s[t - o] : 0;
    __syncthreads();
    s[t] += x;
    __syncthreads();
  }
  p.offp[i] = s[t] - v;
  if (t == 255) p.bsum[b] = s[t];
}

// ================== device: scan_c2 (merged scan_b + scan_c) ====================
__device__ void dev_scan_c2(P& p, int b, char* smem) {
  int* w4 = (int*)smem;
  int t = threadIdx.x;
  int v = (t < b) ? p.bsum[t] : 0;
  #pragma unroll
  for (int o = 1; o < 64; o <<= 1) v += __shfl_xor(v, o);
  if ((t & 63) == 0) w4[t >> 6] = v;
  __syncthreads();
  int base = w4[0] + w4[1] + w4[2] + w4[3];
  int i = b * 256 + t;
  int ov = p.offp[i] + base;
  p.offp[i] = ov;
  p.cur[i] = ov;
  p.dinv[i] = rsqrtf((float)p.cntd[i] + 1.0f);
  if (i == 0) p.offp[HW] = NE;
}

// ============================ device: scatter ====================================
__device__ void dev_scatter(P& p, int b) {
  int e = b * 256 + threadIdx.x;
  if (e < NE) {
    int d = p.e_dst[e], s = p.e_src[e];
    float w = p.dinv[d] * p.dinv[s];
    int pos = atomicAdd(&p.cur[d], 1);
    p.e2[pos] = make_int2(s, __float_as_int(w));
  }
}

// ====================== device: MFMA bf16 GEMM (needs 31744B smem) ===============
__device__ void dev_mgemm(const void* Ap, int a_bf16, int lda,
                          const u16* WT, int ldb, int K,
                          const float* bias, const float* cvec, const float* invn,
                          void* Cp, int c_bf16,
                          float* sums, float* sumsq, int bid, char* smem) {
  u16* As = (u16*)smem;                 // [2][64][40]
  u16* Bs = (u16*)(smem + 10240);       // [2][128][40]
  float* lsum = (float*)(smem + 30720);
  float* lssq = lsum + 128;
  int t = threadIdx.x;
  if (sums && t < 128) { lsum[t] = 0.f; lssq[t] = 0.f; }
  int row0 = bid * 64;
  int ar = t >> 2, ak = (t & 3) * 8;
  u16x8 aReg; u16x8 bReg[2];

  auto loadRegs = [&](int k0) {
    if (a_bf16) {
      aReg = *(const u16x8*)((const u16*)Ap + (size_t)(row0 + ar) * lda + k0 + ak);
    } else {
      const float* ap = (const float*)Ap + (size_t)(row0 + ar) * lda + k0 + ak;
      float4 f0 = *(const float4*)ap;
      float4 f1 = *(const float4*)(ap + 4);
      u16x8 v;
      v[0] = f2b(f0.x); v[1] = f2b(f0.y); v[2] = f2b(f0.z); v[3] = f2b(f0.w);
      v[4] = f2b(f1.x); v[5] = f2b(f1.y); v[6] = f2b(f1.z); v[7] = f2b(f1.w);
      aReg = v;
    }
    #pragma unroll
    for (int it = 0; it < 2; ++it) {
      int slot = t + it * 256;
      int bn = slot >> 2, kg = (slot & 3) * 8;
      bReg[it] = *(const u16x8*)(WT + (size_t)bn * ldb + k0 + kg);
    }
  };
  auto dsWrite = [&](int bq) {
    *(u16x8*)&As[(bq * 64 + ar) * 40 + ak] = aReg;
    #pragma unroll
    for (int it = 0; it < 2; ++it) {
      int slot = t + it * 256;
      int bn = slot >> 2, kg = (slot & 3) * 8;
      *(u16x8*)&Bs[(bq * 128 + bn) * 40 + kg] = bReg[it];
    }
  };

  int lane = t & 63, wvv = t >> 6;
  int m0 = (wvv >> 1) * 32, n0 = (wvv & 1) * 64;
  int fr = lane & 15, fk = (lane >> 4) * 8;
  f32x4 acc[2][4];
  #pragma unroll
  for (int mt = 0; mt < 2; ++mt)
    #pragma unroll
    for (int nt = 0; nt < 4; ++nt)
      acc[mt][nt] = (f32x4){0.f, 0.f, 0.f, 0.f};

  int nch = K >> 5;
  loadRegs(0);
  int cur = 0;
  for (int ch = 0; ch < nch; ++ch) {
    dsWrite(cur);
    __syncthreads();
    if (ch + 1 < nch) loadRegs((ch + 1) << 5);
    s16x8 afr0 = *(const s16x8*)&As[(cur * 64 + m0 + fr) * 40 + fk];
    s16x8 afr1 = *(const s16x8*)&As[(cur * 64 + m0 + 16 + fr) * 40 + fk];
    s16x8 bfr[4];
    #pragma unroll
    for (int nt = 0; nt < 4; ++nt)
      bfr[nt] = *(const s16x8*)&Bs[(cur * 128 + n0 + nt * 16 + fr) * 40 + fk];
    #pragma unroll
    for (int nt = 0; nt < 4; ++nt) {
      acc[0][nt] = __builtin_amdgcn_mfma_f32_16x16x32_bf16(afr0, bfr[nt], acc[0][nt], 0, 0, 0);
      acc[1][nt] = __builtin_amdgcn_mfma_f32_16x16x32_bf16(afr1, bfr[nt], acc[1][nt], 0, 0, 0);
    }
    cur ^= 1;
  }

  float bb4[4], cv4[4];
  #pragma unroll
  for (int nt = 0; nt < 4; ++nt) {
    int c = n0 + nt * 16 + fr;
    bb4[nt] = bias ? bias[c] : 0.f;
    cv4[nt] = cvec ? cvec[c] : 0.f;
  }
  int rg = lane >> 4;
  float cs4[4] = {}, cq4[4] = {};
  #pragma unroll
  for (int mt = 0; mt < 2; ++mt) {
    int rbase = row0 + m0 + mt * 16 + rg * 4;
    float inr[4];
    #pragma unroll
    for (int j = 0; j < 4; ++j) inr[j] = invn ? invn[rbase + j] : 1.f;
    #pragma unroll
    for (int nt = 0; nt < 4; ++nt) {
      int c = n0 + nt * 16 + fr;
      #pragma unroll
      for (int j = 0; j < 4; ++j) {
        float xv = inr[j] * (acc[mt][nt][j] - cv4[nt]) + bb4[nt];
        if (sums) { cs4[nt] += xv; cq4[nt] += xv * xv; }
        if (c_bf16) ((u16*)Cp)[(size_t)(rbase + j) * 128 + c] = f2b(xv);
        else        ((float*)Cp)[(size_t)(rbase + j) * 128 + c] = xv;
      }
    }
  }
  if (sums) {
    __syncthreads();
    #pragma unroll
    for (int nt = 0; nt < 4; ++nt) {
      int c = n0 + nt * 16 + fr;
      atomicAdd(&lsum[c], cs4[nt]);
      atomicAdd(&lssq[c], cq4[nt]);
    }
    __syncthreads();
    if (t < 128) { atomicAdd(&sums[t], lsum[t]); atomicAdd(&sumsq[t], lssq[t]); }
  }
}

// =================== device: superpixel mean-pool (4096B smem) ==================
__device__ void dev_pool2(P& p, int sp, char* smem) {
  float4* part = (float4*)smem;   // [8][32]
  int t = threadIdx.x;
  int l32 = t & 31, g = t >> 5;
  int cnt = p.cntinv[sp];
  const float4* y4 = (const float4*)p.bufA;
  const int* lst = p.seginv + sp * 64;
  float4 acc = make_float4(0.f, 0.f, 0.f, 0.f);
  int r = g;
  for (; r + 8 < cnt; r += 16) {
    int i0 = lst[r], i1 = lst[r + 8];
    float4 a = y4[(size_t)i0 * 32 + l32];
    float4 b = y4[(size_t)i1 * 32 + l32];
    acc.x += a.x + b.x; acc.y += a.y + b.y;
    acc.z += a.z + b.z; acc.w += a.w + b.w;
  }
  for (; r < cnt; r += 8) {
    float4 a = y4[(size_t)lst[r] * 32 + l32];
    acc.x += a.x; acc.y += a.y; acc.z += a.z; acc.w += a.w;
  }
  part[g * 32 + l32] = acc;
  __syncthreads();
  if (g == 0) {
    float4 s = part[l32];
    #pragma unroll
    for (int q = 1; q < 8; ++q) {
      float4 pp = part[q * 32 + l32];
      s.x += pp.x; s.y += pp.y; s.z += pp.z; s.w += pp.w;
    }
    int d0 = l32 * 4;
    const float* sAs = S_A(p);
    const float* sAq = S_A(p) + 128;
    float4 ss = *(const float4*)&sAs[d0];
    float4 sq = *(const float4*)&sAq[d0];
    float inv = 1.0f / (float)cnt;
    float4 o;
    float m, rs;
    m = ss.x / HW; rs = rsqrtf(sq.x / HW - m * m + BN_EPS); o.x = (s.x * inv - m) * rs;
    m = ss.y / HW; rs = rsqrtf(sq.y / HW - m * m + BN_EPS); o.y = (s.y * inv - m) * rs;
    m = ss.z / HW; rs = rsqrtf(sq.z / HW - m * m + BN_EPS); o.z = (s.z * inv - m) * rs;
    m = ss.w / HW; rs = rsqrtf(sq.w / HW - m * m + BN_EPS); o.w = (s.w * inv - m) * rs;
    *(float4*)&p.spA[sp * 128 + d0] = o;
  }
}

// == device: row inv-norms + col-stats of normalized; optional normalized write ==
__device__ void dev_rstats(const float* in, float* norm_out, float* invn,
                           float* sums, float* sumsq, int M,
                           const float* preS, const float* preQ, float precnt,
                           int leaky_in, int bid, int nb, char* smem) {
  float* lsum = (float*)smem;
  float* lssq = lsum + 128;
  int t = threadIdx.x;
  if (t < 128) { lsum[t] = 0.f; lssq[t] = 0.f; }
  __syncthreads();
  int wid = t >> 6, lane = t & 63, d0 = lane * 2;
  float m0 = 0.f, m1 = 0.f, r0 = 1.f, r1 = 1.f;
  if (preS) {
    m0 = preS[d0] / precnt;
    r0 = rsqrtf(preQ[d0] / precnt - m0 * m0 + BN_EPS);
    m1 = preS[d0 + 1] / precnt;
    r1 = rsqrtf(preQ[d0 + 1] / precnt - m1 * m1 + BN_EPS);
  }
  float cs0 = 0.f, cs1 = 0.f, cq0 = 0.f, cq1 = 0.f;
  for (int row = bid * 4 + wid; row < M; row += nb * 4) {
    float2 v = *(const float2*)(in + (size_t)row * 128 + d0);
    v.x = (v.x - m0) * r0;
    v.y = (v.y - m1) * r1;
    if (leaky_in) {
      v.x = (v.x >= 0.f) ? v.x : LSLOPE * v.x;
      v.y = (v.y >= 0.f) ? v.y : LSLOPE * v.y;
    }
    float ss = v.x * v.x + v.y * v.y;
    #pragma unroll
    for (int o = 1; o < 64; o <<= 1) ss += __shfl_xor(ss, o);
    float sc = 1.0f / fmaxf(sqrtf(ss), 1e-12f);
    if (lane == 0) invn[row] = sc;
    float nx = v.x * sc, ny = v.y * sc;
    if (norm_out) *(float2*)(norm_out + (size_t)row * 128 + d0) = make_float2(nx, ny);
    cs0 += nx; cs1 += ny; cq0 += nx * nx; cq1 += ny * ny;
  }
  atomicAdd(&lsum[d0], cs0); atomicAdd(&lsum[d0 + 1], cs1);
  atomicAdd(&lssq[d0], cq0); atomicAdd(&lssq[d0 + 1], cq1);
  __syncthreads();
  if (t < 128) { atomicAdd(&sums[t], lsum[t]); atomicAdd(&sumsq[t], lssq[t]); }
}

// ====== device: fold BN(s) into W -> optional Wpp(f32) / WT(bf16 T) (8192B) =====
__device__ void dev_prepw(const float* sums, const float* sumsq, float cnt,
                          const float* W, const float* base,
                          const float* preS, const float* preQ, float precnt,
                          float* Wpp, u16* WT, float* cvec, float* bp, char* smem) {
  float* redc = (float*)smem;            // [8][128]
  float* redb = redc + 1024;
  int t = threadIdx.x;
  int kq = (t & 31) * 4, jg = t >> 5;
  float cx = 0.f, cy = 0.f, cz = 0.f, cw = 0.f;
  float bx = 0.f, by = 0.f, bz = 0.f, bw = 0.f;
  for (int j = jg; j < 128; j += 8) {
    float m2 = sums[j] / cnt;
    float rs2 = rsqrtf(sumsq[j] / cnt - m2 * m2 + BN_EPS);
    float mA = 0.f, rsA = 1.f;
    if (preS) {
      mA = preS[j] / precnt;
      rsA = rsqrtf(preQ[j] / precnt - mA * mA + BN_EPS);
    }
    float4 w = *(const float4*)&W[j * 128 + kq];
    float sA = rsA * rs2;
    float4 wpp = make_float4(sA * w.x, sA * w.y, sA * w.z, sA * w.w);
    if (Wpp) *(float4*)&Wpp[j * 128 + kq] = wpp;
    if (WT) {
      WT[(size_t)(kq + 0) * 128 + j] = f2b(wpp.x);
      WT[(size_t)(kq + 1) * 128 + j] = f2b(wpp.y);
      WT[(size_t)(kq + 2) * 128 + j] = f2b(wpp.z);
      WT[(size_t)(kq + 3) * 128 + j] = f2b(wpp.w);
    }
    cx = fmaf(mA, wpp.x, cx); cy = fmaf(mA, wpp.y, cy);
    cz = fmaf(mA, wpp.z, cz); cw = fmaf(mA, wpp.w, cw);
    float m2s = m2 * rs2;
    bx = fmaf(m2s, w.x, bx); by = fmaf(m2s, w.y, by);
    bz = fmaf(m2s, w.z, bz); bw = fmaf(m2s, w.w, bw);
  }
  *(float4*)&redc[jg * 128 + kq] = make_float4(cx, cy, cz, cw);
  *(float4*)&redb[jg * 128 + kq] = make_float4(bx, by, bz, bw);
  __syncthreads();
  if (t < 32) {
    int k4 = t * 4;
    float4 sc = *(float4*)&redc[k4];
    float4 sb = *(float4*)&redb[k4];
    #pragma unroll
    for (int g = 1; g < 8; ++g) {
      float4 ac = *(float4*)&redc[g * 128 + k4];
      float4 ab = *(float4*)&redb[g * 128 + k4];
      sc.x += ac.x; sc.y += ac.y; sc.z += ac.z; sc.w += ac.w;
      sb.x += ab.x; sb.y += ab.y; sb.z += ab.z; sb.w += ab.w;
    }
    *(float4*)&cvec[k4] = sc;
    float4 bs = base ? *(const float4*)&base[k4] : make_float4(0, 0, 0, 0);
    *(float4*)&bp[k4] = make_float4(bs.x - sb.x, bs.y - sb.y, bs.z - sb.z, bs.w - sb.w);
  }
}

// ====== device: CSR edge agg (r9 structure: wave-per-row, 8 edges in flight) ====
// norm_bf16==1: l2norm + bf16 out + col-stats; ==0: plain bf16 out (no norm).
__device__ void dev_aggb(P& p, const u16* tbl, const float* bias, void* outp,
                         int norm_bf16, float* sums, float* sumsq,
                         int bid, int nb, char* smem) {
  float* lsum = (float*)smem;
  float* lssq = lsum + 128;
  int t = threadIdx.x;
  if (norm_bf16) {
    if (t < 128) { lsum[t] = 0.f; lssq[t] = 0.f; }
    __syncthreads();
  }
  int wid = t >> 6, lane = t & 63;
  int q = lane >> 4, l16 = lane & 15, c0 = l16 * 8;
  float bb[8];
  #pragma unroll
  for (int j = 0; j < 8; ++j) bb[j] = bias[c0 + j];
  float cs[8] = {}, cq[8] = {};
  for (int i = bid * 4 + wid; i < HW; i += nb * 4) {
    int s0 = p.offp[i], s1 = p.offp[i + 1];
    float di = p.dinv[i];
    u16x8 xi = *(const u16x8*)&tbl[(size_t)i * 128 + c0];
    float acc[8] = {};
    int kk = s0 + q;
    for (; kk + 4 < s1; kk += 8) {
      int2 ea = p.e2[kk], eb = p.e2[kk + 4];
      u16x8 va = *(const u16x8*)&tbl[(size_t)ea.x * 128 + c0];
      u16x8 vb = *(const u16x8*)&tbl[(size_t)eb.x * 128 + c0];
      float wa = __int_as_float(ea.y), wb = __int_as_float(eb.y);
      #pragma unroll
      for (int j = 0; j < 8; ++j) acc[j] = fmaf(wa, b2f(va[j]), acc[j]);
      #pragma unroll
      for (int j = 0; j < 8; ++j) acc[j] = fmaf(wb, b2f(vb[j]), acc[j]);
    }
    for (; kk < s1; kk += 4) {
      int2 e = p.e2[kk];
      u16x8 v = *(const u16x8*)&tbl[(size_t)e.x * 128 + c0];
      float w = __int_as_float(e.y);
      #pragma unroll
      for (int j = 0; j < 8; ++j) acc[j] = fmaf(w, b2f(v[j]), acc[j]);
    }
    #pragma unroll
    for (int j = 0; j < 8; ++j) {
      acc[j] += __shfl_xor(acc[j], 16);
      acc[j] += __shfl_xor(acc[j], 32);
    }
    float inv_deg = di * di;
    float r[8];
    #pragma unroll
    for (int j = 0; j < 8; ++j) {
      r[j] = fmaf(b2f(xi[j]), inv_deg, acc[j]) + bb[j];
      r[j] = (r[j] >= 0.f) ? r[j] : LSLOPE * r[j];
    }
    if (norm_bf16) {
      float ss = 0.f;
      #pragma unroll
      for (int j = 0; j < 8; ++j) ss += r[j] * r[j];
      ss += __shfl_xor(ss, 1); ss += __shfl_xor(ss, 2);
      ss += __shfl_xor(ss, 4); ss += __shfl_xor(ss, 8);
      float sc = 1.0f / fmaxf(sqrtf(ss), 1e-12f);
      if (q == 0) {
        u16x8 o;
        #pragma unroll
        for (int j = 0; j < 8; ++j) {
          r[j] *= sc;
          o[j] = f2b(r[j]);
          cs[j] += r[j]; cq[j] += r[j] * r[j];
        }
        *(u16x8*)&((u16*)outp)[(size_t)i * 128 + c0] = o;
      }
    } else if (q == 0) {
      u16x8 o;
      #pragma unroll
      for (int j = 0; j < 8; ++j) o[j] = f2b(r[j]);
      *(u16x8*)&((u16*)outp)[(size_t)i * 128 + c0] = o;
    }
  }
  if (norm_bf16) {
    if (q == 0) {
      #pragma unroll
      for (int j = 0; j < 8; ++j) {
        atomicAdd(&lsum[c0 + j], cs[j]);
        atomicAdd(&lssq[c0 + j], cq[j]);
      }
    }
    __syncthreads();
    if (t < 128) { atomicAdd(&sums[t], lsum[t]); atomicAdd(&sumsq[t], lssq[t]); }
  }
}

// == device: small GEMM tail: out = Z@W + rs[row]*bp[col]; f32 or bf16 output ====
__device__ void dev_gemm_tail(const float* Z, const float* W,
                              const float* bp, const float* rs,
                              void* out, int out_bf16, int bid) {
  int t = threadIdx.x;
  int c = t & 127, rh = t >> 7;
  int row0 = bid * 16 + rh * 8;
  float acc[8] = {};
  const float* ip = Z + (size_t)row0 * 128;
  #pragma unroll 4
  for (int k = 0; k < 128; ++k) {
    float w = W[k * 128 + c];
    #pragma unroll
    for (int i = 0; i < 8; ++i)
      acc[i] = fmaf(ip[(size_t)i * 128 + k], w, acc[i]);
  }
  float bpc = bp[c];
  #pragma unroll
  for (int i = 0; i < 8; ++i) {
    int row = row0 + i;
    float v = acc[i] + rs[row] * bpc;
    if (out_bf16) ((u16*)out)[(size_t)row * 128 + c] = f2b(v);
    else          ((float*)out)[(size_t)row * 128 + c] = v;
  }
}

// ===== device: split-K GEMM A_norm[1024x1024]@Xn -> atomic out (25088B smem) ====
__device__ void dev_gemm_ks(const float* A, const float* B, float* C,
                            int bid, char* smem) {
  float* As = (float*)smem;            // [32][68]
  float* Bs = As + 32 * 68;            // [32][128]
  int t = threadIdx.x;
  int c0 = (t & 31) * 4;
  int r0 = (t >> 5) * 8;
  int row0 = (bid >> 3) * 64;
  int kbeg = (bid & 7) * 128;
  int kend = kbeg + 128;
  int lr = t >> 2, lkb = (t & 3) * 8;
  float acc[8][4] = {};
  for (int k0 = kbeg; k0 < kend; k0 += 32) {
    __syncthreads();
    for (int idx = t * 4; idx < 32 * 128; idx += 1024)
      *(float4*)&Bs[(idx >> 7) * 128 + (idx & 127)] = *(const float4*)&B[(size_t)k0 * 128 + idx];
    {
      const float* ap = A + (size_t)(row0 + lr) * NSP + k0 + lkb;
      float4 v0 = *(const float4*)ap;
      float4 v1 = *(const float4*)(ap + 4);
      As[(lkb + 0) * 68 + lr] = v0.x; As[(lkb + 1) * 68 + lr] = v0.y;
      As[(lkb + 2) * 68 + lr] = v0.z; As[(lkb + 3) * 68 + lr] = v0.w;
      As[(lkb + 4) * 68 + lr] = v1.x; As[(lkb + 5) * 68 + lr] = v1.y;
      As[(lkb + 6) * 68 + lr] = v1.z; As[(lkb + 7) * 68 + lr] = v1.w;
    }
    __syncthreads();
    #pragma unroll 2
    for (int k = 0; k < 32; ++k) {
      float4 b4 = *(float4*)&Bs[k * 128 + c0];
      float4 a0 = *(float4*)&As[k * 68 + r0];
      float4 a1 = *(float4*)&As[k * 68 + r0 + 4];
      float av[8] = {a0.x, a0.y, a0.z, a0.w, a1.x, a1.y, a1.z, a1.w};
      float bv[4] = {b4.x, b4.y, b4.z, b4.w};
      #pragma unroll
      for (int r = 0; r < 8; ++r)
        #pragma unroll
        for (int c = 0; c < 4; ++c)
          acc[r][c] = fmaf(av[r], bv[c], acc[r][c]);
    }
  }
  #pragma unroll
  for (int r = 0; r < 8; ++r)
    #pragma unroll
    for (int c = 0; c < 4; ++c)
      atomicAdd(&C[(size_t)(row0 + r0 + r) * 128 + c0 + c], acc[r][c]);
}

// ============================ fused dispatches ===================================
__global__ __launch_bounds__(256) void k_za(P p) {        // scan_a | mgemm_pre
  __shared__ __align__(16) char smem[31744];
  int b = blockIdx.x;
  if (b < 256) dev_scan_a(p, b, smem);
  else dev_mgemm((const void*)p.xb, 1, 224, p.WTpre, 224, 224,
                 p.preB, nullptr, nullptr, (void*)p.bufA, 0,
                 S_A(p), S_A(p) + 128, b - 256, smem);
}
__global__ __launch_bounds__(256) void k_zb(P p) {        // scan_c2 | pool2
  __shared__ __align__(16) char smem[4096];
  int b = blockIdx.x;
  if (b < 256) dev_scan_c2(p, b, smem);
  else dev_pool2(p, b - 256, smem);
}
__global__ __launch_bounds__(256) void k_zc(P p) {        // scatter | rstatsHW
  __shared__ __align__(16) char smem[1024];
  int b = blockIdx.x;
  if (b < NE / 256) dev_scatter(p, b);
  else dev_rstats(p.bufA, nullptr, p.invM1, S_M1(p), S_M1(p) + 128, HW,
                  S_A(p), S_A(p) + 128, (float)HW, 0, b - NE / 256, 512, smem);
}
__global__ __launch_bounds__(256) void k_z8(P p) {        // rstatsG1(->xn1) | prepwM1
  __shared__ __align__(16) char smem[8192];
  int b = blockIdx.x;
  if (b < 16) dev_rstats(p.spA, p.xn1, p.invG1, S_G1(p), S_G1(p) + 128, NSP,
                         nullptr, nullptr, 1.f, 0, b, 16, smem);
  else dev_prepw(S_M1(p), S_M1(p) + 128, (float)HW, p.m1W, nullptr,
                 S_A(p), S_A(p) + 128, (float)HW,
                 nullptr, p.WTm1, p.cvM1, p.bpM1, smem);
}
__global__ __launch_bounds__(256) void k_z9(P p) {        // anormZ1 | prepwG1 | mgemmM1
  __shared__ __align__(16) char smem[31744];
  int b = blockIdx.x;
  if (b < 128) dev_gemm_ks(p.A_norm, p.xn1, p.z1p, b, smem);
  else if (b < 129) dev_prepw(S_G1(p), S_G1(p) + 128, (float)NSP, p.g1W, p.g1b,
                              nullptr, nullptr, 1.f, p.WppG1, nullptr, p.cvG1, p.bpG1, smem);
  else dev_mgemm((const void*)p.bufA, 0, 128, p.WTm1, 128, 128,
                 p.bpM1, p.cvM1, p.invM1, (void*)p.xwB, 1,
                 nullptr, nullptr, b - 129, smem);
}
__global__ __launch_bounds__(256) void k_z10(P p) {       // g1tail | aggb1
  __shared__ __align__(16) char smem[1024];
  int b = blockIdx.x;
  if (b < 64) dev_gemm_tail(p.z1p, p.WppG1, p.bpG1, p.rsums, (void*)p.spDp, 0, b);
  else dev_aggb(p, p.xwB, p.m1b, (void*)p.bufN, 1,
                S_M2(p), S_M2(p) + 128, b - 64, 2048, smem);
}
__global__ __launch_bounds__(256) void k_z11(P p) {       // prepwM2 | rstatsG2(->xn2)
  __shared__ __align__(16) char smem[8192];
  int b = blockIdx.x;
  if (b < 1) dev_prepw(S_M2(p), S_M2(p) + 128, (float)HW, p.m2W, nullptr,
                       nullptr, nullptr, 1.f, nullptr, p.WTm2, p.cvM2, p.bpM2, smem);
  else dev_rstats(p.spDp, p.xn2, p.invG2, S_G2(p), S_G2(p) + 128, NSP,
                  nullptr, nullptr, 1.f, 1, b - 1, 16, smem);
}
__global__ __launch_bounds__(256) void k_z12(P p) {       // anormZ2 | prepwG2 | mgemmM2
  __shared__ __align__(16) char smem[31744];
  int b = blockIdx.x;
  if (b < 128) dev_gemm_ks(p.A_norm, p.xn2, p.z2p, b, smem);
  else if (b < 129) dev_prepw(S_G2(p), S_G2(p) + 128, (float)NSP, p.g2W, p.g2b,
                              nullptr, nullptr, 1.f, p.WppG2, nullptr, p.cvG2, p.bpG2, smem);
  else dev_mgemm((const void*)p.bufN, 1, 128, p.WTm2, 128, 128,
                 p.bpM2, p.cvM2, nullptr, (void*)p.xwB, 1,
                 nullptr, nullptr, b - 129, smem);
}
__global__ __launch_bounds__(256) void k_z13(P p) {       // g2tail(bf16) | aggb2(bf16)
  __shared__ __align__(16) char smem[1024];
  int b = blockIdx.x;
  if (b < 64) dev_gemm_tail(p.z2p, p.WppG2, p.bpG2, p.rsums, (void*)p.spHp, 1, b);
  else dev_aggb(p, p.xwB, p.m2b, (void*)p.bufB, 0,
                nullptr, nullptr, b - 64, 2048, smem);
}

// ====== final: (m2_bf16 + leaky(H1p_bf16[seg])) @ out_W + out_b -> softmax ======
__global__ __launch_bounds__(256) void k_final(P p) {
  __shared__ float rb[16][132];
  __shared__ float WL[128 * 16];
  int t = threadIdx.x;
  int row0 = blockIdx.x * 16;
  const u16* m2b = (const u16*)p.bufB;
  const u16* H1b = (const u16*)p.spHp;
  for (int idx = t; idx < 128 * NCLS; idx += 256) WL[idx] = p.oW[idx];
  for (int idx = t; idx < 16 * 128; idx += 256) {
    int r = idx >> 7, d = idx & 127;
    int row = row0 + r;
    float h = b2f(H1b[(size_t)p.seg[row] * 128 + d]);
    h = (h >= 0.f) ? h : LSLOPE * h;
    rb[r][d] = b2f(m2b[(size_t)row * 128 + d]) + h;
  }
  __syncthreads();
  int c = t & 15, r = t >> 4;
  float acc = p.ob[c];
  #pragma unroll 8
  for (int d = 0; d < 128; ++d) acc = fmaf(rb[r][d], WL[d * 16 + c], acc);
  float mx = acc;
  #pragma unroll
  for (int o = 1; o < 16; o <<= 1) mx = fmaxf(mx, __shfl_xor(mx, o));
  float e = expf(acc - mx);
  float s = e;
  #pragma unroll
  for (int o = 1; o < 16; o <<= 1) s += __shfl_xor(s, o);
  p.outp[(size_t)(row0 + r) * NCLS + c] = e / s;
}

// =================================================================================
extern "C" void kernel_launch(void* const* d_in, const int* in_sizes, int n_in,
                              void* d_out, int out_size, void* d_ws, size_t ws_size,
                              hipStream_t stream) {
  P p;
  p.x      = (const float*)d_in[0];
  p.Q      = (const float*)d_in[1];
  p.A_norm = (const float*)d_in[2];
  p.e_src  = (const int*)d_in[3];
  p.e_dst  = (const int*)d_in[3] + NE;
  p.preW = (const float*)d_in[4];  p.preB = (const float*)d_in[5];
  p.g1W  = (const float*)d_in[6];  p.g1b  = (const float*)d_in[7];
  p.g2W  = (const float*)d_in[8];  p.g2b  = (const float*)d_in[9];
  p.m1W  = (const float*)d_in[10]; p.m1b  = (const float*)d_in[11];
  p.m2W  = (const float*)d_in[12]; p.m2b  = (const float*)d_in[13];
  p.oW   = (const float*)d_in[14]; p.ob   = (const float*)d_in[15];
  p.outp = (float*)d_out;

  char* ws = (char*)d_ws;
  size_t o = 0;
  auto alloc = [&](size_t bytes) { size_t r = o; o = (o + bytes + 255) & ~255ULL; return r; };
  size_t bufA_o   = alloc((size_t)HW * 128 * 4);
  size_t bufB_o   = alloc((size_t)HW * 128 * 4);
  // ---- zero group ----
  size_t cntd_o   = alloc((size_t)HW * 4);
  size_t cntinv_o = alloc((size_t)NSP * 4);
  size_t stats_o  = alloc(5 * 256 * 4);
  size_t z1p_o    = alloc((size_t)NSP * 128 * 4);
  size_t z2p_o    = alloc((size_t)NSP * 128 * 4);
  size_t zero_end = o;
  // ---- end zero group ----
  size_t spDp_o   = alloc((size_t)NSP * 128 * 4);
  size_t spHp_o   = alloc((size_t)NSP * 128 * 4);
  size_t seg_o    = alloc((size_t)HW * 4);
  size_t seginv_o = alloc((size_t)HW * 4);
  size_t off_o    = alloc((size_t)(HW + 1) * 4);
  size_t cur_o    = alloc((size_t)HW * 4);
  size_t dinv_o   = alloc((size_t)HW * 4);
  size_t e2_o     = alloc((size_t)NE * 8);
  size_t bsum_o   = alloc(256 * 4);
  size_t spA_o    = alloc((size_t)NSP * 128 * 4);
  size_t xn1_o    = alloc((size_t)NSP * 128 * 4);
  size_t xn2_o    = alloc((size_t)NSP * 128 * 4);
  size_t rsums_o  = alloc((size_t)NSP * 4);
  size_t WppG1_o  = alloc(128 * 128 * 4);
  size_t WppG2_o  = alloc(128 * 128 * 4);
  size_t WTm1_o   = alloc(128 * 128 * 2);
  size_t WTm2_o   = alloc(128 * 128 * 2);
  size_t WTpre_o  = alloc(128 * 224 * 2);
  size_t cvG1_o = alloc(512), bpG1_o = alloc(512);
  size_t cvG2_o = alloc(512), bpG2_o = alloc(512);
  size_t cvM1_o = alloc(512), bpM1_o = alloc(512);
  size_t cvM2_o = alloc(512), bpM2_o = alloc(512);
  size_t invG1_o  = alloc((size_t)NSP * 4);
  size_t invG2_o  = alloc((size_t)NSP * 4);
  size_t invM1_o  = alloc((size_t)HW * 4);
  size_t xb_o     = alloc((size_t)HW * 224 * 2);
  size_t xwB_o    = alloc((size_t)HW * 128 * 2);
  size_t bufN_o   = alloc((size_t)HW * 128 * 2);
  if (o > ws_size) return;

  p.bufA  = (float*)(ws + bufA_o);
  p.bufB  = (float*)(ws + bufB_o);
  p.cntd  = (int*)(ws + cntd_o);
  p.cntinv= (int*)(ws + cntinv_o);
  p.stats = (float*)(ws + stats_o);
  p.z1p   = (float*)(ws + z1p_o);
  p.z2p   = (float*)(ws + z2p_o);
  p.spDp  = (float*)(ws + spDp_o);
  p.spHp  = (float*)(ws + spHp_o);
  p.seg   = (int*)(ws + seg_o);
  p.seginv= (int*)(ws + seginv_o);
  p.offp  = (int*)(ws + off_o);
  p.cur   = (int*)(ws + cur_o);
  p.dinv  = (float*)(ws + dinv_o);
  p.e2    = (int2*)(ws + e2_o);
  p.bsum  = (int*)(ws + bsum_o);
  p.spA   = (float*)(ws + spA_o);
  p.xn1   = (float*)(ws + xn1_o);
  p.xn2   = (float*)(ws + xn2_o);
  p.rsums = (float*)(ws + rsums_o);
  p.WppG1 = (float*)(ws + WppG1_o);
  p.WppG2 = (float*)(ws + WppG2_o);
  p.WTm1  = (u16*)(ws + WTm1_o);
  p.WTm2  = (u16*)(ws + WTm2_o);
  p.WTpre = (u16*)(ws + WTpre_o);
  p.cvG1 = (float*)(ws + cvG1_o); p.bpG1 = (float*)(ws + bpG1_o);
  p.cvG2 = (float*)(ws + cvG2_o); p.bpG2 = (float*)(ws + bpG2_o);
  p.cvM1 = (float*)(ws + cvM1_o); p.bpM1 = (float*)(ws + bpM1_o);
  p.cvM2 = (float*)(ws + cvM2_o); p.bpM2 = (float*)(ws + bpM2_o);
  p.invG1 = (float*)(ws + invG1_o);
  p.invG2 = (float*)(ws + invG2_o);
  p.invM1 = (float*)(ws + invM1_o);
  p.xb   = (u16*)(ws + xb_o);
  p.xwB  = (u16*)(ws + xwB_o);
  p.bufN = (u16*)(ws + bufN_o);

  hipMemsetAsync(ws + cntd_o, 0, zero_end - cntd_o, stream);

  hipLaunchKernelGGL(k_setup, dim3(NQB + NDB + CXB + CWB + RSB), dim3(256), 0, stream, p);
  hipLaunchKernelGGL(k_za,    dim3(256 + HW / 64), dim3(256), 0, stream, p);
  hipLaunchKernelGGL(k_zb,    dim3(256 + NSP), dim3(256), 0, stream, p);
  hipLaunchKernelGGL(k_zc,    dim3(NE / 256 + 512), dim3(256), 0, stream, p);
  hipLaunchKernelGGL(k_z8,    dim3(17), dim3(256), 0, stream, p);
  hipLaunchKernelGGL(k_z9,    dim3(129 + HW / 64), dim3(256), 0, stream, p);
  hipLaunchKernelGGL(k_z10,   dim3(64 + 2048), dim3(256), 0, stream, p);
  hipLaunchKernelGGL(k_z11,   dim3(17), dim3(256), 0, stream, p);
  hipLaunchKernelGGL(k_z12,   dim3(129 + HW / 64), dim3(256), 0, stream, p);
  hipLaunchKernelGGL(k_z13,   dim3(64 + 2048), dim3(256), 0, stream, p);
  hipLaunchKernelGGL(k_final, dim3(HW / 16), dim3(256), 0, stream, p);
}